// Round 1
// baseline (876.174 us; speedup 1.0000x reference)
//
#include <hip/hip_runtime.h>
#include <math.h>

#define NLVL  16
#define TSZ   (1u << 19)
#define TMASK (TSZ - 1u)

struct ResArr { int m1[NLVL * 4]; };  // per level, per dim: res-1

typedef short  short8  __attribute__((ext_vector_type(8)));
typedef float  float4v __attribute__((ext_vector_type(4)));

static __device__ __forceinline__ unsigned short f2bf(float f) {
    unsigned u = __float_as_uint(f);
    return (unsigned short)((u + 0x7fffu + ((u >> 16) & 1u)) >> 16);  // RNE
}

// ---------------------------------------------------------------------------
// Encode body (round-9 structure): mixed 16B-pair/8B gathers via PRIMES[0]==1
// corner-pair trick. ~12 L2 requests per point-level; runs at ~98% of the
// 1-req/cy-per-L2-channel service roofline when level-major dispatched.
// ---------------------------------------------------------------------------
static __device__ __forceinline__
void encode_point(const float4* __restrict__ x,
                  const float2* __restrict__ table,
                  unsigned*     __restrict__ featbf,  // [NLVL][N] bf16 pairs
                  int N, int l, int n, const ResArr& res)
{
    if (n >= N) return;

    const float4 xv = x[n];
    const float px[4] = {xv.x, xv.y, xv.z, xv.w};

    int   bi[4];
    float fr[4], om[4];
    #pragma unroll
    for (int d = 0; d < 4; ++d) {
        const int r = res.m1[l * 4 + d];       // wave-uniform -> scalar
        const float pos = px[d] * (float)r;
        const float fb  = floorf(pos);
        fr[d] = pos - fb;
        om[d] = 1.0f - fr[d];
        bi[d] = (int)fb;
    }
    const float2* tl  = table + (size_t)l * TSZ;
    const float4* tl4 = (const float4*)tl;

    unsigned hrest[8];
    #pragma unroll
    for (int p = 0; p < 8; ++p) {
        const int c1 = bi[1] + ( p       & 1);
        const int c2 = bi[2] + ((p >> 1) & 1);
        const int c3 = bi[3] + ((p >> 2) & 1);
        hrest[p] = ((unsigned)c1 * 2654435761u)
                 ^ ((unsigned)c2 * 805459861u)
                 ^ ((unsigned)c3 * 3674653429u);
    }

    float2 fv[16];   // fv[2p] = dim0-offset 0, fv[2p+1] = dim0-offset 1
    if ((bi[0] & 1) == 0) {
        #pragma unroll
        for (int p = 0; p < 8; ++p) {
            const unsigned h = ((unsigned)bi[0] ^ hrest[p]) & TMASK;
            const float4 q = tl4[h >> 1];
            const bool odd = (h & 1);
            fv[2 * p]     = odd ? make_float2(q.z, q.w) : make_float2(q.x, q.y);
            fv[2 * p + 1] = odd ? make_float2(q.x, q.y) : make_float2(q.z, q.w);
        }
    } else {
        #pragma unroll
        for (int p = 0; p < 8; ++p) {
            const unsigned hA = ((unsigned)bi[0]       ^ hrest[p]) & TMASK;
            const unsigned hB = ((unsigned)(bi[0] + 1) ^ hrest[p]) & TMASK;
            fv[2 * p]     = tl[hA];
            fv[2 * p + 1] = tl[hB];
        }
    }

    float wt[16];
    #pragma unroll
    for (int c = 0; c < 16; ++c) {
        float w = ( c       & 1) ? fr[0] : om[0];
        w      *= ((c >> 1) & 1) ? fr[1] : om[1];
        w      *= ((c >> 2) & 1) ? fr[2] : om[2];
        w      *= ((c >> 3) & 1) ? fr[3] : om[3];
        wt[c] = w;
    }

    float a0 = 0.0f, a1 = 0.0f;
    #pragma unroll
    for (int c = 0; c < 16; ++c) {           // same order as reference einsum
        a0 = fmaf(wt[c], fv[c].x, a0);
        a1 = fmaf(wt[c], fv[c].y, a1);
    }
    featbf[(size_t)l * N + n] = (unsigned)f2bf(a0) | ((unsigned)f2bf(a1) << 16);
}

__global__ __launch_bounds__(256, 4)
void ingp_encode(const float4* __restrict__ x,
                 const float2* __restrict__ table,
                 unsigned*     __restrict__ featbf,
                 int N, int pointBase, int chunksPerLevel, ResArr res)
{
    const int l     = blockIdx.x / chunksPerLevel;
    const int chunk = blockIdx.x - l * chunksPerLevel;
    encode_point(x, table, featbf, N, l, pointBase + chunk * 256 + (int)threadIdx.x, res);
}

// ---------------------------------------------------------------------------
// MFMA MLP body — round-8 structure + depth-2 prefetch ring. Identical math
// to the verified round-11 kernel; factored into a device function so it can
// run both standalone (D3) and role-split inside the pipeline dispatch (D2).
// ---------------------------------------------------------------------------
#define TILE_BODY(P0, A0)                                                     \
{                                                                             \
    float4v acc0[4];                                                          \
    _Pragma("unroll")                                                         \
    for (int t = 0; t < 4; ++t) {                                             \
        acc0[t] = (float4v){0.f, 0.f, 0.f, 0.f};                              \
        acc0[t] = __builtin_amdgcn_mfma_f32_16x16x32_bf16(A0, w0f[t], acc0[t], 0, 0, 0); \
    }                                                                         \
    _Pragma("unroll")                                                         \
    for (int t = 0; t < 4; ++t)                                               \
        _Pragma("unroll")                                                     \
        for (int r = 0; r < 4; ++r)                                           \
            *(unsigned short*)(hbase + (q * 4 + r) * 144 + (t * 16 + nn) * 2) = \
                f2bf(fmaxf(acc0[t][r], 0.0f));                                \
    short8 a1[2];                                                             \
    _Pragma("unroll")                                                         \
    for (int s = 0; s < 2; ++s)                                               \
        a1[s] = *(const short8*)(hbase + nn * 144 + s * 64 + q * 16);         \
    float4v acc1[4];                                                          \
    _Pragma("unroll")                                                         \
    for (int t = 0; t < 4; ++t) {                                             \
        acc1[t] = (float4v){0.f, 0.f, 0.f, 0.f};                              \
        _Pragma("unroll")                                                     \
        for (int s = 0; s < 2; ++s)                                           \
            acc1[t] = __builtin_amdgcn_mfma_f32_16x16x32_bf16(a1[s], w1f[s][t], acc1[t], 0, 0, 0); \
    }                                                                         \
    _Pragma("unroll")                                                         \
    for (int t = 0; t < 4; ++t)                                               \
        _Pragma("unroll")                                                     \
        for (int r = 0; r < 4; ++r)                                           \
            *(unsigned short*)(hbase + (q * 4 + r) * 144 + (t * 16 + nn) * 2) = \
                f2bf(fmaxf(acc1[t][r], 0.0f));                                \
    short8 a2[2];                                                             \
    _Pragma("unroll")                                                         \
    for (int s = 0; s < 2; ++s)                                               \
        a2[s] = *(const short8*)(hbase + nn * 144 + s * 64 + q * 16);         \
    float4v acc2[4];                                                          \
    _Pragma("unroll")                                                         \
    for (int t = 0; t < 4; ++t) {                                             \
        acc2[t] = (float4v){0.f, 0.f, 0.f, 0.f};                              \
        _Pragma("unroll")                                                     \
        for (int s = 0; s < 2; ++s)                                           \
            acc2[t] = __builtin_amdgcn_mfma_f32_16x16x32_bf16(a2[s], w2f[s][t], acc2[t], 0, 0, 0); \
    }                                                                         \
    _Pragma("unroll")                                                         \
    for (int t = 0; t < 4; ++t)                                               \
        _Pragma("unroll")                                                     \
        for (int r = 0; r < 4; ++r)                                           \
            *(unsigned short*)(hbase + (q * 4 + r) * 144 + (t * 16 + nn) * 2) = \
                f2bf(fmaxf(acc2[t][r], 0.0f));                                \
    short8 a3[2];                                                             \
    _Pragma("unroll")                                                         \
    for (int s = 0; s < 2; ++s)                                               \
        a3[s] = *(const short8*)(hbase + nn * 144 + s * 64 + q * 16);         \
    float4v oc = (float4v){0.f, 0.f, 0.f, 0.f};                               \
    _Pragma("unroll")                                                         \
    for (int s = 0; s < 2; ++s)                                               \
        oc = __builtin_amdgcn_mfma_f32_16x16x32_bf16(a3[s], wof[s], oc, 0, 0, 0); \
    if (nn < 3) {                                                             \
        _Pragma("unroll")                                                     \
        for (int r = 0; r < 4; ++r) {                                         \
            const int pt = (P0) + q * 4 + r;                                  \
            if (pt < N) out[pt * 3 + nn] = oc[r] + bias;                      \
        }                                                                     \
    }                                                                         \
}

static __device__ __forceinline__
void mlp_block_body(const unsigned* __restrict__ featbf,  // [NLVL][N]
                    const float*    __restrict__ w0,
                    const float*    __restrict__ w1,
                    const float*    __restrict__ w2,
                    const float*    __restrict__ wout,
                    const float*    __restrict__ bout,
                    float*          __restrict__ out,
                    int N, int firstTile, char* lds_raw)
{
    const int tid  = (int)threadIdx.x;
    const int wave = tid >> 6;
    const int lane = tid & 63;
    const int q    = lane >> 4;     // quad: K-chunk selector
    const int nn   = lane & 15;     // neuron / point within tile
    char* hbase = lds_raw + wave * (16 * 144);

    short8 w0f[4];
    #pragma unroll
    for (int t = 0; t < 4; ++t) {
        const float* wr = w0 + (t * 16 + nn) * 32 + q * 8;
        #pragma unroll
        for (int e = 0; e < 8; ++e) w0f[t][e] = (short)f2bf(wr[e]);
    }
    short8 w1f[2][4], w2f[2][4];
    #pragma unroll
    for (int s = 0; s < 2; ++s) {
        #pragma unroll
        for (int t = 0; t < 4; ++t) {
            const float* wr1 = w1 + (t * 16 + nn) * 64 + s * 32 + q * 8;
            const float* wr2 = w2 + (t * 16 + nn) * 64 + s * 32 + q * 8;
            #pragma unroll
            for (int e = 0; e < 8; ++e) {
                w1f[s][t][e] = (short)f2bf(wr1[e]);
                w2f[s][t][e] = (short)f2bf(wr2[e]);
            }
        }
    }
    short8 wof[2];
    #pragma unroll
    for (int s = 0; s < 2; ++s) {
        #pragma unroll
        for (int e = 0; e < 8; ++e) {
            wof[s][e] = (nn < 3) ? (short)f2bf(wout[nn * 64 + s * 32 + q * 8 + e])
                                 : (short)0;
        }
    }
    const float bias = (nn < 3) ? bout[nn] : 0.0f;

    const int base = firstTile + wave * 8;   // tilesPerWave = 8

    // ---- prologue: prefetch tiles 0 and 1 ----
    unsigned ufA[4], ufB[4];
    {
        const int pA = (base * 16 < N) ? (base * 16 + nn) : 0;
        const int pB = ((base + 1) * 16 < N) ? ((base + 1) * 16 + nn) : 0;
        #pragma unroll
        for (int v = 0; v < 4; ++v) {
            ufA[v] = featbf[(size_t)(q * 4 + v) * N + pA];
            ufB[v] = featbf[(size_t)(q * 4 + v) * N + pB];
        }
    }

    for (int it = 0; it < 8; it += 2) {
        const int p0A = (base + it) * 16;
        if (p0A >= N) break;

        // tile it: unpack A-frag, then immediately issue prefetch for it+2
        short8 a0A;
        #pragma unroll
        for (int v = 0; v < 4; ++v) {
            a0A[2 * v]     = (short)(ufA[v] & 0xffffu);
            a0A[2 * v + 1] = (short)(ufA[v] >> 16);
        }
        {
            const int p0n = (base + it + 2) * 16;
            const bool more = (it + 2 < 8) && (p0n < N);
            const int pn = more ? (p0n + nn) : 0;
            #pragma unroll
            for (int v = 0; v < 4; ++v)
                ufA[v] = featbf[(size_t)(q * 4 + v) * N + pn];
        }
        TILE_BODY(p0A, a0A)

        // tile it+1
        const int p0B = (base + it + 1) * 16;
        if (p0B < N) {
            short8 a0B;
            #pragma unroll
            for (int v = 0; v < 4; ++v) {
                a0B[2 * v]     = (short)(ufB[v] & 0xffffu);
                a0B[2 * v + 1] = (short)(ufB[v] >> 16);
            }
            {
                const int p0n = (base + it + 3) * 16;
                const bool more = (it + 3 < 8) && (p0n < N);
                const int pn = more ? (p0n + nn) : 0;
                #pragma unroll
                for (int v = 0; v < 4; ++v)
                    ufB[v] = featbf[(size_t)(q * 4 + v) * N + pn];
            }
            TILE_BODY(p0B, a0B)
        }
    }
}

__global__ __launch_bounds__(256, 2)
void ingp_mlp_mfma(const unsigned* __restrict__ featbf,
                   const float*    __restrict__ w0,
                   const float*    __restrict__ w1,
                   const float*    __restrict__ w2,
                   const float*    __restrict__ wout,
                   const float*    __restrict__ bout,
                   float*          __restrict__ out,
                   int N, int firstTileBase)
{
    __shared__ char lds_raw[4 * 16 * 144];
    mlp_block_body(featbf, w0, w1, w2, wout, bout, out, N,
                   firstTileBase + (int)blockIdx.x * 32, lds_raw);
}

// ---------------------------------------------------------------------------
// Pipeline dispatch D2: encode points [A,N) WHILE running the MLP for [0,A).
// Roles are interleaved across blockIdx (Bresenham mix) so the in-order block
// dispatcher keeps both roles resident: encode waves sit stalled on vmcnt
// backpressure (the L2-channel request roofline), and MLP blocks fill the
// otherwise-idle VALU/MFMA/LDS issue slots on the same CUs. No cross-block
// dependency inside this dispatch: M reads only D1's features, E writes only
// the B-range features.
// ---------------------------------------------------------------------------
__global__ __launch_bounds__(256, 2)
void ingp_pipe(const float4* __restrict__ x,
               const float2* __restrict__ table,
               unsigned*     __restrict__ featbf,
               const float*  __restrict__ w0,
               const float*  __restrict__ w1,
               const float*  __restrict__ w2,
               const float*  __restrict__ wout,
               const float*  __restrict__ bout,
               float*        __restrict__ out,
               int N, int pointBaseE, int chunksPerLevelB, int MB, int G,
               ResArr res)
{
    __shared__ char lds_raw[4 * 16 * 144];
    const int b = (int)blockIdx.x;
    const long long t0 = (long long)b * MB;
    const int mlow  = (int)(t0 / G);
    const int mhigh = (int)((t0 + MB) / G);
    if (mhigh > mlow) {
        // MLP role: m_idx = mlow, covers tiles [mlow*32, mlow*32+32) of [0,A)
        mlp_block_body(featbf, w0, w1, w2, wout, bout, out, N, mlow * 32, lds_raw);
    } else {
        // encode role: e_idx = b - (#M blocks before b) = b - mlow
        const int e     = b - mlow;
        const int l     = e / chunksPerLevelB;
        const int chunk = e - l * chunksPerLevelB;
        encode_point(x, table, featbf, N, l,
                     pointBaseE + chunk * 256 + (int)threadIdx.x, res);
    }
}

// ---------------------------------------------------------------------------
// Fallback: round-2 fused kernel (used only if ws is too small for features).
// ---------------------------------------------------------------------------
__global__ __launch_bounds__(256, 2)
void ingp_fused(const float4* __restrict__ x,
                const float2* __restrict__ table,
                const float*  __restrict__ w0,
                const float*  __restrict__ w1,
                const float*  __restrict__ w2,
                const float*  __restrict__ wout,
                const float*  __restrict__ bout,
                float*        __restrict__ out,
                int N, ResArr res)
{
    const int n = blockIdx.x * blockDim.x + threadIdx.x;
    if (n >= N) return;

    const float4 xv = x[n];
    const float px[4] = {xv.x, xv.y, xv.z, xv.w};

    float h1[64];
    #pragma unroll
    for (int j = 0; j < 64; ++j) h1[j] = 0.0f;

    float a0p = 0.0f, a1p = 0.0f;

    #pragma unroll 1
    for (int l = 0; l < NLVL; ++l) {
        int   rm[4], bi[4];
        float fr[4], om[4];
        #pragma unroll
        for (int d = 0; d < 4; ++d) {
            const int r = res.m1[l * 4 + d];
            rm[d] = r;
            const float pos = px[d] * (float)r;
            const float fb  = floorf(pos);
            fr[d] = pos - fb;
            om[d] = 1.0f - fr[d];
            bi[d] = (int)fb;
        }
        const float2* tl = table + (size_t)l * TSZ;

        float2 fv[16];
        float  wt[16];
        #pragma unroll
        for (int c = 0; c < 16; ++c) {
            int c0 = bi[0] + ( c       & 1);
            int c1 = bi[1] + ((c >> 1) & 1);
            int c2 = bi[2] + ((c >> 2) & 1);
            int c3 = bi[3] + ((c >> 3) & 1);
            c0 = min(max(c0, 0), rm[0]);
            c1 = min(max(c1, 0), rm[1]);
            c2 = min(max(c2, 0), rm[2]);
            c3 = min(max(c3, 0), rm[3]);
            const unsigned hh = (unsigned)c0
                              ^ ((unsigned)c1 * 2654435761u)
                              ^ ((unsigned)c2 * 805459861u)
                              ^ ((unsigned)c3 * 3674653429u);
            fv[c] = tl[hh & TMASK];
            float w = ( c       & 1) ? fr[0] : om[0];
            w      *= ((c >> 1) & 1) ? fr[1] : om[1];
            w      *= ((c >> 2) & 1) ? fr[2] : om[2];
            w      *= ((c >> 3) & 1) ? fr[3] : om[3];
            wt[c] = w;
        }
        {
            const int lp = (l == 0) ? 0 : (l - 1);
            const float* w0c = w0 + 2 * lp;
            #pragma unroll
            for (int j = 0; j < 64; ++j)
                h1[j] = fmaf(w0c[j * 32], a0p, fmaf(w0c[j * 32 + 1], a1p, h1[j]));
        }
        float a0 = 0.0f, a1 = 0.0f;
        #pragma unroll
        for (int c = 0; c < 16; ++c) {
            a0 = fmaf(wt[c], fv[c].x, a0);
            a1 = fmaf(wt[c], fv[c].y, a1);
        }
        a0p = a0; a1p = a1;
    }
    {
        const float* w0c = w0 + 2 * (NLVL - 1);
        #pragma unroll
        for (int j = 0; j < 64; ++j)
            h1[j] = fmaf(w0c[j * 32], a0p, fmaf(w0c[j * 32 + 1], a1p, h1[j]));
    }
    #pragma unroll
    for (int j = 0; j < 64; ++j) h1[j] = fmaxf(h1[j], 0.0f);

    float h2[64];
    #pragma unroll
    for (int j = 0; j < 64; ++j) {
        float acc = 0.0f;
        const float* wr = w1 + j * 64;
        #pragma unroll
        for (int i = 0; i < 64; ++i) acc = fmaf(wr[i], h1[i], acc);
        h2[j] = fmaxf(acc, 0.0f);
    }
    float h3[64];
    #pragma unroll
    for (int j = 0; j < 64; ++j) {
        float acc = 0.0f;
        const float* wr = w2 + j * 64;
        #pragma unroll
        for (int i = 0; i < 64; ++i) acc = fmaf(wr[i], h2[i], acc);
        h3[j] = fmaxf(acc, 0.0f);
    }
    float o[3];
    #pragma unroll
    for (int k = 0; k < 3; ++k) {
        float acc = bout[k];
        const float* wr = wout + k * 64;
        #pragma unroll
        for (int i = 0; i < 64; ++i) acc = fmaf(wr[i], h3[i], acc);
        o[k] = acc;
    }
    out[n * 3 + 0] = o[0];
    out[n * 3 + 1] = o[1];
    out[n * 3 + 2] = o[2];
}

extern "C" void kernel_launch(void* const* d_in, const int* in_sizes, int n_in,
                              void* d_out, int out_size, void* d_ws, size_t ws_size,
                              hipStream_t stream) {
    (void)n_in; (void)out_size;

    const float* x     = (const float*)d_in[0];
    const float* table = (const float*)d_in[1];
    const float* w0    = (const float*)d_in[2];
    const float* w1    = (const float*)d_in[3];
    const float* w2    = (const float*)d_in[4];
    const float* wout  = (const float*)d_in[5];
    const float* bout  = (const float*)d_in[6];
    float* out = (float*)d_out;

    const int N = in_sizes[0] / 4;

    // Replicate numpy's float64 resolution computation bit-for-bit (same
    // glibc pow). Levels 5/10/15 of dim 3 sit on exact integer boundaries
    // (8^(5/15)==2), so floor() must see the same double as numpy produced.
    ResArr res;
    for (int d = 0; d < 4; ++d) {
        const double minr = 16.0;
        const double maxr = (d == 3) ? 128.0 : 256.0;
        const double growth = pow(maxr / minr, 1.0 / (double)(NLVL - 1));
        for (int l = 0; l < NLVL; ++l) {
            const int r = (int)floor(minr * pow(growth, (double)l));
            res.m1[l * 4 + d] = r - 1;
        }
    }

    const size_t featBytes = (size_t)NLVL * (size_t)N * sizeof(unsigned);

    if (ws_size >= featBytes) {
        unsigned* featbf = (unsigned*)d_ws;

        // A = pipeline split point: encode [0,A) first, then overlap
        // MLP([0,A)) with encode([A,N)). Must be a multiple of 512
        // (256-pt encode chunks AND 32-tile MLP blocks).
        const int A = (int)((((long long)N * 3) / 4) / 512 * 512);
        const bool pipe_ok = (N % 256 == 0) && (A > 0) && (A < N);

        if (pipe_ok) {
            // ---- D1: encode points [0, A), level-major (L2-coherent) ----
            const int chunksA = A / 256;
            hipLaunchKernelGGL(ingp_encode, dim3(NLVL * chunksA), dim3(256),
                               0, stream, (const float4*)x, (const float2*)table,
                               featbf, N, 0, chunksA, res);

            // ---- D2: encode [A,N)  ||  MLP [0,A), roles interleaved ----
            const int chunksB = (N - A) / 256;
            const int EB = NLVL * chunksB;
            const int MB = A / 512;            // MLP blocks (32 tiles each)
            const int G  = EB + MB;
            hipLaunchKernelGGL(ingp_pipe, dim3(G), dim3(256), 0, stream,
                               (const float4*)x, (const float2*)table, featbf,
                               w0, w1, w2, wout, bout, out,
                               N, A, chunksB, MB, G, res);

            // ---- D3: MLP [A, N) ----
            const int tilesB  = (N - A + 15) / 16;
            const int wavesB  = (tilesB + 7) / 8;
            const int blocksB = (wavesB + 3) / 4;
            hipLaunchKernelGGL(ingp_mlp_mfma, dim3(blocksB), dim3(256), 0, stream,
                               featbf, w0, w1, w2, wout, bout, out, N, A / 16);
        } else {
            // original 2-dispatch path
            const int chunksPerLevel = (N + 255) / 256;
            hipLaunchKernelGGL(ingp_encode, dim3(NLVL * chunksPerLevel), dim3(256),
                               0, stream, (const float4*)x, (const float2*)table,
                               featbf, N, 0, chunksPerLevel, res);
            const int tiles  = (N + 15) / 16;
            const int waves  = (tiles + 7) / 8;
            const int blocks = (waves + 3) / 4;
            hipLaunchKernelGGL(ingp_mlp_mfma, dim3(blocks), dim3(256), 0, stream,
                               featbf, w0, w1, w2, wout, bout, out, N, 0);
        }
    } else {
        hipLaunchKernelGGL(ingp_fused, dim3((N + 255) / 256), dim3(256), 0, stream,
                           (const float4*)x, (const float2*)table,
                           w0, w1, w2, wout, bout, out, N, res);
    }
}

// Round 2
// 745.973 us; speedup vs baseline: 1.1745x; 1.1745x over previous
//
#include <hip/hip_runtime.h>
#include <math.h>

#define NLVL  16
#define TSZ   (1u << 19)
#define TMASK (TSZ - 1u)

struct ResArr { int m1[NLVL * 4]; };  // per level, per dim: res-1

typedef short  short8  __attribute__((ext_vector_type(8)));
typedef float  float4v __attribute__((ext_vector_type(4)));

static __device__ __forceinline__ unsigned short f2bf(float f) {
    unsigned u = __float_as_uint(f);
    return (unsigned short)((u + 0x7fffu + ((u >> 16) & 1u)) >> 16);  // RNE
}

// ---------------------------------------------------------------------------
// Table conversion: f32 pairs (8B/entry) -> packed bf16 pairs (4B/entry).
// Runs once per call (~48 MB of traffic, ~8 us). Halves table footprint to
// 2 MB/level and enables 16B-group corner pairing in the encode.
// ---------------------------------------------------------------------------
__global__ __launch_bounds__(256)
void cvt_table(const float4* __restrict__ t, uint2* __restrict__ o, int totalPairs)
{
    for (int i = blockIdx.x * 256 + (int)threadIdx.x; i < totalPairs;
         i += gridDim.x * 256) {
        const float4 e = t[i];
        o[i] = make_uint2((unsigned)f2bf(e.x) | ((unsigned)f2bf(e.y) << 16),
                          (unsigned)f2bf(e.z) | ((unsigned)f2bf(e.w) << 16));
    }
}

// ---------------------------------------------------------------------------
// Encode, bf16-table version. Request count per point-level:
//   bi0 even        (50%): 8 x 8B   (pair {h, h^1} in one aligned 8B)
//   bi0 % 4 == 1    (25%): 8 x 16B  (pair {h, h^3} in one aligned 16B group)
//   bi0 % 4 == 3    (25%): 16 x 4B  (partner mask >= 7, separate entries)
// avg 10 req vs 12 for the f32-table version -> ~x0.83 at the L2-channel
// request-service roofline. f32 accumulation order identical to reference.
// ---------------------------------------------------------------------------
static __device__ __forceinline__
void encode_point_bf16(const float4*   __restrict__ x,
                       const unsigned* __restrict__ tbl,     // [NLVL][TSZ] bf16 pairs
                       unsigned*       __restrict__ featbf,  // [NLVL][N] bf16 pairs
                       int N, int l, int n, const ResArr& res)
{
    if (n >= N) return;

    const float4 xv = x[n];
    const float px[4] = {xv.x, xv.y, xv.z, xv.w};

    int   bi[4];
    float fr[4], om[4];
    #pragma unroll
    for (int d = 0; d < 4; ++d) {
        const int r = res.m1[l * 4 + d];       // wave-uniform -> scalar
        const float pos = px[d] * (float)r;
        const float fb  = floorf(pos);
        fr[d] = pos - fb;
        om[d] = 1.0f - fr[d];
        bi[d] = (int)fb;
    }
    const unsigned* tl  = tbl + (size_t)l * TSZ;
    const uint2*    tl2 = (const uint2*)tl;
    const uint4*    tl4 = (const uint4*)tl;

    unsigned hrest[8];
    #pragma unroll
    for (int p = 0; p < 8; ++p) {
        const int c1 = bi[1] + ( p       & 1);
        const int c2 = bi[2] + ((p >> 1) & 1);
        const int c3 = bi[3] + ((p >> 2) & 1);
        hrest[p] = ((unsigned)c1 * 2654435761u)
                 ^ ((unsigned)c2 * 805459861u)
                 ^ ((unsigned)c3 * 3674653429u);
    }

    const int b0 = bi[0];
    unsigned ea[8], eb[8];   // packed bf16 pairs: dim0-offset 0 / offset 1

    if ((b0 & 1) == 0) {
        // bi0 even: partner index = h ^ 1 -> one aligned 8B load per pair
        #pragma unroll
        for (int p = 0; p < 8; ++p) {
            const unsigned h = ((unsigned)b0 ^ hrest[p]) & TMASK;
            const uint2 q = tl2[h >> 1];
            ea[p] = (h & 1u) ? q.y : q.x;
            eb[p] = (h & 1u) ? q.x : q.y;
        }
    } else if ((b0 & 3) == 1) {
        // bi0 % 4 == 1: partner = h ^ 3 -> same aligned 16B group of 4 entries
        #pragma unroll
        for (int p = 0; p < 8; ++p) {
            const unsigned hA = ((unsigned)b0 ^ hrest[p]) & TMASK;
            const uint4 q = tl4[hA >> 2];
            const unsigned jA  = hA & 3u;
            const unsigned loA = (jA & 2u) ? q.z : q.x;
            const unsigned hiA = (jA & 2u) ? q.w : q.y;
            const unsigned loB = (jA & 2u) ? q.x : q.z;
            const unsigned hiB = (jA & 2u) ? q.y : q.w;
            ea[p] = (jA & 1u) ? hiA : loA;
            eb[p] = (jA & 1u) ? loB : hiB;
        }
    } else {
        // bi0 % 4 == 3: partner differs in >= 3 low bits -> two 4B loads
        #pragma unroll
        for (int p = 0; p < 8; ++p) {
            const unsigned hA = ((unsigned)b0       ^ hrest[p]) & TMASK;
            const unsigned hB = ((unsigned)(b0 + 1) ^ hrest[p]) & TMASK;
            ea[p] = tl[hA];
            eb[p] = tl[hB];
        }
    }

    float2 fv[16];   // fv[2p] = dim0-offset 0, fv[2p+1] = dim0-offset 1
    #pragma unroll
    for (int p = 0; p < 8; ++p) {
        fv[2 * p]     = make_float2(__uint_as_float(ea[p] << 16),
                                    __uint_as_float(ea[p] & 0xffff0000u));
        fv[2 * p + 1] = make_float2(__uint_as_float(eb[p] << 16),
                                    __uint_as_float(eb[p] & 0xffff0000u));
    }

    float wt[16];
    #pragma unroll
    for (int c = 0; c < 16; ++c) {
        float w = ( c       & 1) ? fr[0] : om[0];
        w      *= ((c >> 1) & 1) ? fr[1] : om[1];
        w      *= ((c >> 2) & 1) ? fr[2] : om[2];
        w      *= ((c >> 3) & 1) ? fr[3] : om[3];
        wt[c] = w;
    }

    float a0 = 0.0f, a1 = 0.0f;
    #pragma unroll
    for (int c = 0; c < 16; ++c) {           // same order as reference einsum
        a0 = fmaf(wt[c], fv[c].x, a0);
        a1 = fmaf(wt[c], fv[c].y, a1);
    }
    featbf[(size_t)l * N + n] = (unsigned)f2bf(a0) | ((unsigned)f2bf(a1) << 16);
}

__global__ __launch_bounds__(256, 4)
void ingp_encode_bf16(const float4*   __restrict__ x,
                      const unsigned* __restrict__ tbl,
                      unsigned*       __restrict__ featbf,
                      int N, int chunksPerLevel, ResArr res)
{
    const int l     = blockIdx.x / chunksPerLevel;
    const int chunk = blockIdx.x - l * chunksPerLevel;
    encode_point_bf16(x, tbl, featbf, N, l, chunk * 256 + (int)threadIdx.x, res);
}

// ---------------------------------------------------------------------------
// f32-table encode (fallback when ws can't hold the bf16 table copy).
// Round-9 verified structure.
// ---------------------------------------------------------------------------
static __device__ __forceinline__
void encode_point_f32(const float4* __restrict__ x,
                      const float2* __restrict__ table,
                      unsigned*     __restrict__ featbf,
                      int N, int l, int n, const ResArr& res)
{
    if (n >= N) return;

    const float4 xv = x[n];
    const float px[4] = {xv.x, xv.y, xv.z, xv.w};

    int   bi[4];
    float fr[4], om[4];
    #pragma unroll
    for (int d = 0; d < 4; ++d) {
        const int r = res.m1[l * 4 + d];
        const float pos = px[d] * (float)r;
        const float fb  = floorf(pos);
        fr[d] = pos - fb;
        om[d] = 1.0f - fr[d];
        bi[d] = (int)fb;
    }
    const float2* tl  = table + (size_t)l * TSZ;
    const float4* tl4 = (const float4*)tl;

    unsigned hrest[8];
    #pragma unroll
    for (int p = 0; p < 8; ++p) {
        const int c1 = bi[1] + ( p       & 1);
        const int c2 = bi[2] + ((p >> 1) & 1);
        const int c3 = bi[3] + ((p >> 2) & 1);
        hrest[p] = ((unsigned)c1 * 2654435761u)
                 ^ ((unsigned)c2 * 805459861u)
                 ^ ((unsigned)c3 * 3674653429u);
    }

    float2 fv[16];
    if ((bi[0] & 1) == 0) {
        #pragma unroll
        for (int p = 0; p < 8; ++p) {
            const unsigned h = ((unsigned)bi[0] ^ hrest[p]) & TMASK;
            const float4 q = tl4[h >> 1];
            const bool odd = (h & 1);
            fv[2 * p]     = odd ? make_float2(q.z, q.w) : make_float2(q.x, q.y);
            fv[2 * p + 1] = odd ? make_float2(q.x, q.y) : make_float2(q.z, q.w);
        }
    } else {
        #pragma unroll
        for (int p = 0; p < 8; ++p) {
            const unsigned hA = ((unsigned)bi[0]       ^ hrest[p]) & TMASK;
            const unsigned hB = ((unsigned)(bi[0] + 1) ^ hrest[p]) & TMASK;
            fv[2 * p]     = tl[hA];
            fv[2 * p + 1] = tl[hB];
        }
    }

    float wt[16];
    #pragma unroll
    for (int c = 0; c < 16; ++c) {
        float w = ( c       & 1) ? fr[0] : om[0];
        w      *= ((c >> 1) & 1) ? fr[1] : om[1];
        w      *= ((c >> 2) & 1) ? fr[2] : om[2];
        w      *= ((c >> 3) & 1) ? fr[3] : om[3];
        wt[c] = w;
    }

    float a0 = 0.0f, a1 = 0.0f;
    #pragma unroll
    for (int c = 0; c < 16; ++c) {
        a0 = fmaf(wt[c], fv[c].x, a0);
        a1 = fmaf(wt[c], fv[c].y, a1);
    }
    featbf[(size_t)l * N + n] = (unsigned)f2bf(a0) | ((unsigned)f2bf(a1) << 16);
}

__global__ __launch_bounds__(256, 4)
void ingp_encode_f32(const float4* __restrict__ x,
                     const float2* __restrict__ table,
                     unsigned*     __restrict__ featbf,
                     int N, int chunksPerLevel, ResArr res)
{
    const int l     = blockIdx.x / chunksPerLevel;
    const int chunk = blockIdx.x - l * chunksPerLevel;
    encode_point_f32(x, table, featbf, N, l, chunk * 256 + (int)threadIdx.x, res);
}

// ---------------------------------------------------------------------------
// MFMA MLP — verified round-8 structure + depth-2 prefetch ring.
// ---------------------------------------------------------------------------
#define TILE_BODY(P0, A0)                                                     \
{                                                                             \
    float4v acc0[4];                                                          \
    _Pragma("unroll")                                                         \
    for (int t = 0; t < 4; ++t) {                                             \
        acc0[t] = (float4v){0.f, 0.f, 0.f, 0.f};                              \
        acc0[t] = __builtin_amdgcn_mfma_f32_16x16x32_bf16(A0, w0f[t], acc0[t], 0, 0, 0); \
    }                                                                         \
    _Pragma("unroll")                                                         \
    for (int t = 0; t < 4; ++t)                                               \
        _Pragma("unroll")                                                     \
        for (int r = 0; r < 4; ++r)                                           \
            *(unsigned short*)(hbase + (q * 4 + r) * 144 + (t * 16 + nn) * 2) = \
                f2bf(fmaxf(acc0[t][r], 0.0f));                                \
    short8 a1[2];                                                             \
    _Pragma("unroll")                                                         \
    for (int s = 0; s < 2; ++s)                                               \
        a1[s] = *(const short8*)(hbase + nn * 144 + s * 64 + q * 16);         \
    float4v acc1[4];                                                          \
    _Pragma("unroll")                                                         \
    for (int t = 0; t < 4; ++t) {                                             \
        acc1[t] = (float4v){0.f, 0.f, 0.f, 0.f};                              \
        _Pragma("unroll")                                                     \
        for (int s = 0; s < 2; ++s)                                           \
            acc1[t] = __builtin_amdgcn_mfma_f32_16x16x32_bf16(a1[s], w1f[s][t], acc1[t], 0, 0, 0); \
    }                                                                         \
    _Pragma("unroll")                                                         \
    for (int t = 0; t < 4; ++t)                                               \
        _Pragma("unroll")                                                     \
        for (int r = 0; r < 4; ++r)                                           \
            *(unsigned short*)(hbase + (q * 4 + r) * 144 + (t * 16 + nn) * 2) = \
                f2bf(fmaxf(acc1[t][r], 0.0f));                                \
    short8 a2[2];                                                             \
    _Pragma("unroll")                                                         \
    for (int s = 0; s < 2; ++s)                                               \
        a2[s] = *(const short8*)(hbase + nn * 144 + s * 64 + q * 16);         \
    float4v acc2[4];                                                          \
    _Pragma("unroll")                                                         \
    for (int t = 0; t < 4; ++t) {                                             \
        acc2[t] = (float4v){0.f, 0.f, 0.f, 0.f};                              \
        _Pragma("unroll")                                                     \
        for (int s = 0; s < 2; ++s)                                           \
            acc2[t] = __builtin_amdgcn_mfma_f32_16x16x32_bf16(a2[s], w2f[s][t], acc2[t], 0, 0, 0); \
    }                                                                         \
    _Pragma("unroll")                                                         \
    for (int t = 0; t < 4; ++t)                                               \
        _Pragma("unroll")                                                     \
        for (int r = 0; r < 4; ++r)                                           \
            *(unsigned short*)(hbase + (q * 4 + r) * 144 + (t * 16 + nn) * 2) = \
                f2bf(fmaxf(acc2[t][r], 0.0f));                                \
    short8 a3[2];                                                             \
    _Pragma("unroll")                                                         \
    for (int s = 0; s < 2; ++s)                                               \
        a3[s] = *(const short8*)(hbase + nn * 144 + s * 64 + q * 16);         \
    float4v oc = (float4v){0.f, 0.f, 0.f, 0.f};                               \
    _Pragma("unroll")                                                         \
    for (int s = 0; s < 2; ++s)                                               \
        oc = __builtin_amdgcn_mfma_f32_16x16x32_bf16(a3[s], wof[s], oc, 0, 0, 0); \
    if (nn < 3) {                                                             \
        _Pragma("unroll")                                                     \
        for (int r = 0; r < 4; ++r) {                                         \
            const int pt = (P0) + q * 4 + r;                                  \
            if (pt < N) out[pt * 3 + nn] = oc[r] + bias;                      \
        }                                                                     \
    }                                                                         \
}

static __device__ __forceinline__
void mlp_block_body(const unsigned* __restrict__ featbf,  // [NLVL][N]
                    const float*    __restrict__ w0,
                    const float*    __restrict__ w1,
                    const float*    __restrict__ w2,
                    const float*    __restrict__ wout,
                    const float*    __restrict__ bout,
                    float*          __restrict__ out,
                    int N, int firstTile, char* lds_raw)
{
    const int tid  = (int)threadIdx.x;
    const int wave = tid >> 6;
    const int lane = tid & 63;
    const int q    = lane >> 4;     // quad: K-chunk selector
    const int nn   = lane & 15;     // neuron / point within tile
    char* hbase = lds_raw + wave * (16 * 144);

    short8 w0f[4];
    #pragma unroll
    for (int t = 0; t < 4; ++t) {
        const float* wr = w0 + (t * 16 + nn) * 32 + q * 8;
        #pragma unroll
        for (int e = 0; e < 8; ++e) w0f[t][e] = (short)f2bf(wr[e]);
    }
    short8 w1f[2][4], w2f[2][4];
    #pragma unroll
    for (int s = 0; s < 2; ++s) {
        #pragma unroll
        for (int t = 0; t < 4; ++t) {
            const float* wr1 = w1 + (t * 16 + nn) * 64 + s * 32 + q * 8;
            const float* wr2 = w2 + (t * 16 + nn) * 64 + s * 32 + q * 8;
            #pragma unroll
            for (int e = 0; e < 8; ++e) {
                w1f[s][t][e] = (short)f2bf(wr1[e]);
                w2f[s][t][e] = (short)f2bf(wr2[e]);
            }
        }
    }
    short8 wof[2];
    #pragma unroll
    for (int s = 0; s < 2; ++s) {
        #pragma unroll
        for (int e = 0; e < 8; ++e) {
            wof[s][e] = (nn < 3) ? (short)f2bf(wout[nn * 64 + s * 32 + q * 8 + e])
                                 : (short)0;
        }
    }
    const float bias = (nn < 3) ? bout[nn] : 0.0f;

    const int base = firstTile + wave * 8;   // tilesPerWave = 8

    // ---- prologue: prefetch tiles 0 and 1 ----
    unsigned ufA[4], ufB[4];
    {
        const int pA = (base * 16 < N) ? (base * 16 + nn) : 0;
        const int pB = ((base + 1) * 16 < N) ? ((base + 1) * 16 + nn) : 0;
        #pragma unroll
        for (int v = 0; v < 4; ++v) {
            ufA[v] = featbf[(size_t)(q * 4 + v) * N + pA];
            ufB[v] = featbf[(size_t)(q * 4 + v) * N + pB];
        }
    }

    for (int it = 0; it < 8; it += 2) {
        const int p0A = (base + it) * 16;
        if (p0A >= N) break;

        // tile it: unpack A-frag, then immediately issue prefetch for it+2
        short8 a0A;
        #pragma unroll
        for (int v = 0; v < 4; ++v) {
            a0A[2 * v]     = (short)(ufA[v] & 0xffffu);
            a0A[2 * v + 1] = (short)(ufA[v] >> 16);
        }
        {
            const int p0n = (base + it + 2) * 16;
            const bool more = (it + 2 < 8) && (p0n < N);
            const int pn = more ? (p0n + nn) : 0;
            #pragma unroll
            for (int v = 0; v < 4; ++v)
                ufA[v] = featbf[(size_t)(q * 4 + v) * N + pn];
        }
        TILE_BODY(p0A, a0A)

        // tile it+1
        const int p0B = (base + it + 1) * 16;
        if (p0B < N) {
            short8 a0B;
            #pragma unroll
            for (int v = 0; v < 4; ++v) {
                a0B[2 * v]     = (short)(ufB[v] & 0xffffu);
                a0B[2 * v + 1] = (short)(ufB[v] >> 16);
            }
            {
                const int p0n = (base + it + 3) * 16;
                const bool more = (it + 3 < 8) && (p0n < N);
                const int pn = more ? (p0n + nn) : 0;
                #pragma unroll
                for (int v = 0; v < 4; ++v)
                    ufB[v] = featbf[(size_t)(q * 4 + v) * N + pn];
            }
            TILE_BODY(p0B, a0B)
        }
    }
}

__global__ __launch_bounds__(256, 2)
void ingp_mlp_mfma(const unsigned* __restrict__ featbf,
                   const float*    __restrict__ w0,
                   const float*    __restrict__ w1,
                   const float*    __restrict__ w2,
                   const float*    __restrict__ wout,
                   const float*    __restrict__ bout,
                   float*          __restrict__ out,
                   int N)
{
    __shared__ char lds_raw[4 * 16 * 144];
    mlp_block_body(featbf, w0, w1, w2, wout, bout, out, N,
                   (int)blockIdx.x * 32, lds_raw);
}

// ---------------------------------------------------------------------------
// Fallback: round-2 fused kernel (used only if ws is too small for features).
// ---------------------------------------------------------------------------
__global__ __launch_bounds__(256, 2)
void ingp_fused(const float4* __restrict__ x,
                const float2* __restrict__ table,
                const float*  __restrict__ w0,
                const float*  __restrict__ w1,
                const float*  __restrict__ w2,
                const float*  __restrict__ wout,
                const float*  __restrict__ bout,
                float*        __restrict__ out,
                int N, ResArr res)
{
    const int n = blockIdx.x * blockDim.x + threadIdx.x;
    if (n >= N) return;

    const float4 xv = x[n];
    const float px[4] = {xv.x, xv.y, xv.z, xv.w};

    float h1[64];
    #pragma unroll
    for (int j = 0; j < 64; ++j) h1[j] = 0.0f;

    float a0p = 0.0f, a1p = 0.0f;

    #pragma unroll 1
    for (int l = 0; l < NLVL; ++l) {
        int   rm[4], bi[4];
        float fr[4], om[4];
        #pragma unroll
        for (int d = 0; d < 4; ++d) {
            const int r = res.m1[l * 4 + d];
            rm[d] = r;
            const float pos = px[d] * (float)r;
            const float fb  = floorf(pos);
            fr[d] = pos - fb;
            om[d] = 1.0f - fr[d];
            bi[d] = (int)fb;
        }
        const float2* tl = table + (size_t)l * TSZ;

        float2 fv[16];
        float  wt[16];
        #pragma unroll
        for (int c = 0; c < 16; ++c) {
            int c0 = bi[0] + ( c       & 1);
            int c1 = bi[1] + ((c >> 1) & 1);
            int c2 = bi[2] + ((c >> 2) & 1);
            int c3 = bi[3] + ((c >> 3) & 1);
            c0 = min(max(c0, 0), rm[0]);
            c1 = min(max(c1, 0), rm[1]);
            c2 = min(max(c2, 0), rm[2]);
            c3 = min(max(c3, 0), rm[3]);
            const unsigned hh = (unsigned)c0
                              ^ ((unsigned)c1 * 2654435761u)
                              ^ ((unsigned)c2 * 805459861u)
                              ^ ((unsigned)c3 * 3674653429u);
            fv[c] = tl[hh & TMASK];
            float w = ( c       & 1) ? fr[0] : om[0];
            w      *= ((c >> 1) & 1) ? fr[1] : om[1];
            w      *= ((c >> 2) & 1) ? fr[2] : om[2];
            w      *= ((c >> 3) & 1) ? fr[3] : om[3];
            wt[c] = w;
        }
        {
            const int lp = (l == 0) ? 0 : (l - 1);
            const float* w0c = w0 + 2 * lp;
            #pragma unroll
            for (int j = 0; j < 64; ++j)
                h1[j] = fmaf(w0c[j * 32], a0p, fmaf(w0c[j * 32 + 1], a1p, h1[j]));
        }
        float a0 = 0.0f, a1 = 0.0f;
        #pragma unroll
        for (int c = 0; c < 16; ++c) {
            a0 = fmaf(wt[c], fv[c].x, a0);
            a1 = fmaf(wt[c], fv[c].y, a1);
        }
        a0p = a0; a1p = a1;
    }
    {
        const float* w0c = w0 + 2 * (NLVL - 1);
        #pragma unroll
        for (int j = 0; j < 64; ++j)
            h1[j] = fmaf(w0c[j * 32], a0p, fmaf(w0c[j * 32 + 1], a1p, h1[j]));
    }
    #pragma unroll
    for (int j = 0; j < 64; ++j) h1[j] = fmaxf(h1[j], 0.0f);

    float h2[64];
    #pragma unroll
    for (int j = 0; j < 64; ++j) {
        float acc = 0.0f;
        const float* wr = w1 + j * 64;
        #pragma unroll
        for (int i = 0; i < 64; ++i) acc = fmaf(wr[i], h1[i], acc);
        h2[j] = fmaxf(acc, 0.0f);
    }
    float h3[64];
    #pragma unroll
    for (int j = 0; j < 64; ++j) {
        float acc = 0.0f;
        const float* wr = w2 + j * 64;
        #pragma unroll
        for (int i = 0; i < 64; ++i) acc = fmaf(wr[i], h2[i], acc);
        h3[j] = fmaxf(acc, 0.0f);
    }
    float o[3];
    #pragma unroll
    for (int k = 0; k < 3; ++k) {
        float acc = bout[k];
        const float* wr = wout + k * 64;
        #pragma unroll
        for (int i = 0; i < 64; ++i) acc = fmaf(wr[i], h3[i], acc);
        o[k] = acc;
    }
    out[n * 3 + 0] = o[0];
    out[n * 3 + 1] = o[1];
    out[n * 3 + 2] = o[2];
}

extern "C" void kernel_launch(void* const* d_in, const int* in_sizes, int n_in,
                              void* d_out, int out_size, void* d_ws, size_t ws_size,
                              hipStream_t stream) {
    (void)n_in; (void)out_size;

    const float* x     = (const float*)d_in[0];
    const float* table = (const float*)d_in[1];
    const float* w0    = (const float*)d_in[2];
    const float* w1    = (const float*)d_in[3];
    const float* w2    = (const float*)d_in[4];
    const float* wout  = (const float*)d_in[5];
    const float* bout  = (const float*)d_in[6];
    float* out = (float*)d_out;

    const int N = in_sizes[0] / 4;

    // Replicate numpy's float64 resolution computation bit-for-bit (same
    // glibc pow). Levels 5/10/15 of dim 3 sit on exact integer boundaries
    // (8^(5/15)==2), so floor() must see the same double as numpy produced.
    ResArr res;
    for (int d = 0; d < 4; ++d) {
        const double minr = 16.0;
        const double maxr = (d == 3) ? 128.0 : 256.0;
        const double growth = pow(maxr / minr, 1.0 / (double)(NLVL - 1));
        for (int l = 0; l < NLVL; ++l) {
            const int r = (int)floor(minr * pow(growth, (double)l));
            res.m1[l * 4 + d] = r - 1;
        }
    }

    const size_t tblBytes  = (size_t)NLVL * TSZ * sizeof(unsigned);      // 32 MiB
    const size_t featBytes = (size_t)NLVL * (size_t)N * sizeof(unsigned);
    const int chunksPerLevel = (N + 255) / 256;

    if (ws_size >= tblBytes + featBytes) {
        unsigned* tblbf  = (unsigned*)d_ws;
        unsigned* featbf = (unsigned*)((char*)d_ws + tblBytes);

        hipLaunchKernelGGL(cvt_table, dim3(2048), dim3(256), 0, stream,
                           (const float4*)table, (uint2*)tblbf,
                           (int)(NLVL * TSZ / 2));

        hipLaunchKernelGGL(ingp_encode_bf16, dim3(NLVL * chunksPerLevel), dim3(256),
                           0, stream, (const float4*)x, tblbf,
                           featbf, N, chunksPerLevel, res);

        const int tiles  = (N + 15) / 16;
        const int waves  = (tiles + 7) / 8;
        const int blocks = (waves + 3) / 4;
        hipLaunchKernelGGL(ingp_mlp_mfma, dim3(blocks), dim3(256), 0, stream,
                           featbf, w0, w1, w2, wout, bout, out, N);
    } else if (ws_size >= featBytes) {
        unsigned* featbf = (unsigned*)d_ws;
        hipLaunchKernelGGL(ingp_encode_f32, dim3(NLVL * chunksPerLevel), dim3(256),
                           0, stream, (const float4*)x, (const float2*)table,
                           featbf, N, chunksPerLevel, res);

        const int tiles  = (N + 15) / 16;
        const int waves  = (tiles + 7) / 8;
        const int blocks = (waves + 3) / 4;
        hipLaunchKernelGGL(ingp_mlp_mfma, dim3(blocks), dim3(256), 0, stream,
                           featbf, w0, w1, w2, wout, bout, out, N);
    } else {
        hipLaunchKernelGGL(ingp_fused, dim3((N + 255) / 256), dim3(256), 0, stream,
                           (const float4*)x, (const float2*)table,
                           w0, w1, w2, wout, bout, out, N, res);
    }
}

// Round 3
// 728.815 us; speedup vs baseline: 1.2022x; 1.0235x over previous
//
#include <hip/hip_runtime.h>
#include <math.h>

#define NLVL  16
#define TSZ   (1u << 19)
#define TMASK (TSZ - 1u)

struct ResArr { int m1[NLVL * 4]; };  // per level, per dim: res-1

typedef short  short8  __attribute__((ext_vector_type(8)));
typedef float  float4v __attribute__((ext_vector_type(4)));

static __device__ __forceinline__ unsigned short f2bf(float f) {
    unsigned u = __float_as_uint(f);
    return (unsigned short)((u + 0x7fffu + ((u >> 16) & 1u)) >> 16);  // RNE
}

// ---------------------------------------------------------------------------
// Table conversion: f32 pairs (8B/entry) -> packed bf16 pairs (4B/entry).
// Runs once per call (~48 MB of traffic, ~10 us). Halves table footprint to
// 2 MB/level and enables 16B-group corner pairing in the encode.
// ---------------------------------------------------------------------------
__global__ __launch_bounds__(256)
void cvt_table(const float4* __restrict__ t, uint2* __restrict__ o, int totalPairs)
{
    for (int i = blockIdx.x * 256 + (int)threadIdx.x; i < totalPairs;
         i += gridDim.x * 256) {
        const float4 e = t[i];
        o[i] = make_uint2((unsigned)f2bf(e.x) | ((unsigned)f2bf(e.y) << 16),
                          (unsigned)f2bf(e.z) | ((unsigned)f2bf(e.w) << 16));
    }
}

// ---------------------------------------------------------------------------
// Encode, bf16-table version (verified round-2: 580 us, ~96% of the ~300 G
// req/s L2-channel service roofline). Request count per point-level:
//   bi0 even        (50%): 8 x 8B   (pair {h, h^1} in one aligned 8B)
//   bi0 % 4 == 1    (25%): 8 x 16B  (pair {h, h^3} in one aligned 16B group)
//   bi0 % 4 == 3    (25%): 16 x 4B  (partner mask >= 7, separate entries)
// ---------------------------------------------------------------------------
static __device__ __forceinline__
void encode_point_bf16(const float4*   __restrict__ x,
                       const unsigned* __restrict__ tbl,     // [NLVL][TSZ] bf16 pairs
                       unsigned*       __restrict__ featbf,  // [NLVL][N] bf16 pairs
                       int N, int l, int n, const ResArr& res)
{
    if (n >= N) return;

    const float4 xv = x[n];
    const float px[4] = {xv.x, xv.y, xv.z, xv.w};

    int   bi[4];
    float fr[4], om[4];
    #pragma unroll
    for (int d = 0; d < 4; ++d) {
        const int r = res.m1[l * 4 + d];       // wave-uniform -> scalar
        const float pos = px[d] * (float)r;
        const float fb  = floorf(pos);
        fr[d] = pos - fb;
        om[d] = 1.0f - fr[d];
        bi[d] = (int)fb;
    }
    const unsigned* tl  = tbl + (size_t)l * TSZ;
    const uint2*    tl2 = (const uint2*)tl;
    const uint4*    tl4 = (const uint4*)tl;

    unsigned hrest[8];
    #pragma unroll
    for (int p = 0; p < 8; ++p) {
        const int c1 = bi[1] + ( p       & 1);
        const int c2 = bi[2] + ((p >> 1) & 1);
        const int c3 = bi[3] + ((p >> 2) & 1);
        hrest[p] = ((unsigned)c1 * 2654435761u)
                 ^ ((unsigned)c2 * 805459861u)
                 ^ ((unsigned)c3 * 3674653429u);
    }

    const int b0 = bi[0];
    unsigned ea[8], eb[8];   // packed bf16 pairs: dim0-offset 0 / offset 1

    if ((b0 & 1) == 0) {
        // bi0 even: partner index = h ^ 1 -> one aligned 8B load per pair
        #pragma unroll
        for (int p = 0; p < 8; ++p) {
            const unsigned h = ((unsigned)b0 ^ hrest[p]) & TMASK;
            const uint2 q = tl2[h >> 1];
            ea[p] = (h & 1u) ? q.y : q.x;
            eb[p] = (h & 1u) ? q.x : q.y;
        }
    } else if ((b0 & 3) == 1) {
        // bi0 % 4 == 1: partner = h ^ 3 -> same aligned 16B group of 4 entries
        #pragma unroll
        for (int p = 0; p < 8; ++p) {
            const unsigned hA = ((unsigned)b0 ^ hrest[p]) & TMASK;
            const uint4 q = tl4[hA >> 2];
            const unsigned jA  = hA & 3u;
            const unsigned loA = (jA & 2u) ? q.z : q.x;
            const unsigned hiA = (jA & 2u) ? q.w : q.y;
            const unsigned loB = (jA & 2u) ? q.x : q.z;
            const unsigned hiB = (jA & 2u) ? q.y : q.w;
            ea[p] = (jA & 1u) ? hiA : loA;
            eb[p] = (jA & 1u) ? loB : hiB;
        }
    } else {
        // bi0 % 4 == 3: partner differs in >= 3 low bits -> two 4B loads
        #pragma unroll
        for (int p = 0; p < 8; ++p) {
            const unsigned hA = ((unsigned)b0       ^ hrest[p]) & TMASK;
            const unsigned hB = ((unsigned)(b0 + 1) ^ hrest[p]) & TMASK;
            ea[p] = tl[hA];
            eb[p] = tl[hB];
        }
    }

    float2 fv[16];   // fv[2p] = dim0-offset 0, fv[2p+1] = dim0-offset 1
    #pragma unroll
    for (int p = 0; p < 8; ++p) {
        fv[2 * p]     = make_float2(__uint_as_float(ea[p] << 16),
                                    __uint_as_float(ea[p] & 0xffff0000u));
        fv[2 * p + 1] = make_float2(__uint_as_float(eb[p] << 16),
                                    __uint_as_float(eb[p] & 0xffff0000u));
    }

    float wt[16];
    #pragma unroll
    for (int c = 0; c < 16; ++c) {
        float w = ( c       & 1) ? fr[0] : om[0];
        w      *= ((c >> 1) & 1) ? fr[1] : om[1];
        w      *= ((c >> 2) & 1) ? fr[2] : om[2];
        w      *= ((c >> 3) & 1) ? fr[3] : om[3];
        wt[c] = w;
    }

    float a0 = 0.0f, a1 = 0.0f;
    #pragma unroll
    for (int c = 0; c < 16; ++c) {           // same order as reference einsum
        a0 = fmaf(wt[c], fv[c].x, a0);
        a1 = fmaf(wt[c], fv[c].y, a1);
    }
    featbf[(size_t)l * N + n] = (unsigned)f2bf(a0) | ((unsigned)f2bf(a1) << 16);
}

__global__ __launch_bounds__(256, 4)
void ingp_encode_bf16(const float4*   __restrict__ x,
                      const unsigned* __restrict__ tbl,
                      unsigned*       __restrict__ featbf,
                      int N, int chunksPerLevel, ResArr res)
{
    const int l     = blockIdx.x / chunksPerLevel;
    const int chunk = blockIdx.x - l * chunksPerLevel;
    encode_point_bf16(x, tbl, featbf, N, l, chunk * 256 + (int)threadIdx.x, res);
}

// ---------------------------------------------------------------------------
// f32-table encode (fallback when ws can't hold the bf16 table copy).
// ---------------------------------------------------------------------------
static __device__ __forceinline__
void encode_point_f32(const float4* __restrict__ x,
                      const float2* __restrict__ table,
                      unsigned*     __restrict__ featbf,
                      int N, int l, int n, const ResArr& res)
{
    if (n >= N) return;

    const float4 xv = x[n];
    const float px[4] = {xv.x, xv.y, xv.z, xv.w};

    int   bi[4];
    float fr[4], om[4];
    #pragma unroll
    for (int d = 0; d < 4; ++d) {
        const int r = res.m1[l * 4 + d];
        const float pos = px[d] * (float)r;
        const float fb  = floorf(pos);
        fr[d] = pos - fb;
        om[d] = 1.0f - fr[d];
        bi[d] = (int)fb;
    }
    const float2* tl  = table + (size_t)l * TSZ;
    const float4* tl4 = (const float4*)tl;

    unsigned hrest[8];
    #pragma unroll
    for (int p = 0; p < 8; ++p) {
        const int c1 = bi[1] + ( p       & 1);
        const int c2 = bi[2] + ((p >> 1) & 1);
        const int c3 = bi[3] + ((p >> 2) & 1);
        hrest[p] = ((unsigned)c1 * 2654435761u)
                 ^ ((unsigned)c2 * 805459861u)
                 ^ ((unsigned)c3 * 3674653429u);
    }

    float2 fv[16];
    if ((bi[0] & 1) == 0) {
        #pragma unroll
        for (int p = 0; p < 8; ++p) {
            const unsigned h = ((unsigned)bi[0] ^ hrest[p]) & TMASK;
            const float4 q = tl4[h >> 1];
            const bool odd = (h & 1);
            fv[2 * p]     = odd ? make_float2(q.z, q.w) : make_float2(q.x, q.y);
            fv[2 * p + 1] = odd ? make_float2(q.x, q.y) : make_float2(q.z, q.w);
        }
    } else {
        #pragma unroll
        for (int p = 0; p < 8; ++p) {
            const unsigned hA = ((unsigned)bi[0]       ^ hrest[p]) & TMASK;
            const unsigned hB = ((unsigned)(bi[0] + 1) ^ hrest[p]) & TMASK;
            fv[2 * p]     = tl[hA];
            fv[2 * p + 1] = tl[hB];
        }
    }

    float wt[16];
    #pragma unroll
    for (int c = 0; c < 16; ++c) {
        float w = ( c       & 1) ? fr[0] : om[0];
        w      *= ((c >> 1) & 1) ? fr[1] : om[1];
        w      *= ((c >> 2) & 1) ? fr[2] : om[2];
        w      *= ((c >> 3) & 1) ? fr[3] : om[3];
        wt[c] = w;
    }

    float a0 = 0.0f, a1 = 0.0f;
    #pragma unroll
    for (int c = 0; c < 16; ++c) {
        a0 = fmaf(wt[c], fv[c].x, a0);
        a1 = fmaf(wt[c], fv[c].y, a1);
    }
    featbf[(size_t)l * N + n] = (unsigned)f2bf(a0) | ((unsigned)f2bf(a1) << 16);
}

__global__ __launch_bounds__(256, 4)
void ingp_encode_f32(const float4* __restrict__ x,
                     const float2* __restrict__ table,
                     unsigned*     __restrict__ featbf,
                     int N, int chunksPerLevel, ResArr res)
{
    const int l     = blockIdx.x / chunksPerLevel;
    const int chunk = blockIdx.x - l * chunksPerLevel;
    encode_point_f32(x, table, featbf, N, l, chunk * 256 + (int)threadIdx.x, res);
}

// ---------------------------------------------------------------------------
// MFMA MLP — round-8 structure + depth-2 feat prefetch ring + (round 3)
// w2/wout fragments staged in block-shared LDS instead of per-wave VGPRs.
// Saves ~40 VGPRs -> __launch_bounds__(256,4): 16 waves/CU instead of 8,
// doubling latency hiding on the feat-load / LDS-round-trip chains.
// idx0 is laundered through empty inline asm per tile so LICM cannot hoist
// the loop-invariant LDS weight reads back into registers.
// ---------------------------------------------------------------------------
#define TILE_BODY(P0, A0)                                                     \
{                                                                             \
    asm volatile("" : "+v"(idx0));   /* block LICM of the wlds reads below */ \
    float4v acc0[4];                                                          \
    _Pragma("unroll")                                                         \
    for (int t = 0; t < 4; ++t) {                                             \
        acc0[t] = (float4v){0.f, 0.f, 0.f, 0.f};                              \
        acc0[t] = __builtin_amdgcn_mfma_f32_16x16x32_bf16(A0, w0f[t], acc0[t], 0, 0, 0); \
    }                                                                         \
    _Pragma("unroll")                                                         \
    for (int t = 0; t < 4; ++t)                                               \
        _Pragma("unroll")                                                     \
        for (int r = 0; r < 4; ++r)                                           \
            *(unsigned short*)(hbase + (q * 4 + r) * 144 + (t * 16 + nn) * 2) = \
                f2bf(fmaxf(acc0[t][r], 0.0f));                                \
    short8 a1[2];                                                             \
    _Pragma("unroll")                                                         \
    for (int s = 0; s < 2; ++s)                                               \
        a1[s] = *(const short8*)(hbase + nn * 144 + s * 64 + q * 16);         \
    float4v acc1[4];                                                          \
    _Pragma("unroll")                                                         \
    for (int t = 0; t < 4; ++t) {                                             \
        acc1[t] = (float4v){0.f, 0.f, 0.f, 0.f};                              \
        _Pragma("unroll")                                                     \
        for (int s = 0; s < 2; ++s)                                           \
            acc1[t] = __builtin_amdgcn_mfma_f32_16x16x32_bf16(a1[s], w1f[s][t], acc1[t], 0, 0, 0); \
    }                                                                         \
    _Pragma("unroll")                                                         \
    for (int t = 0; t < 4; ++t)                                               \
        _Pragma("unroll")                                                     \
        for (int r = 0; r < 4; ++r)                                           \
            *(unsigned short*)(hbase + (q * 4 + r) * 144 + (t * 16 + nn) * 2) = \
                f2bf(fmaxf(acc1[t][r], 0.0f));                                \
    short8 a2[2];                                                             \
    _Pragma("unroll")                                                         \
    for (int s = 0; s < 2; ++s)                                               \
        a2[s] = *(const short8*)(hbase + nn * 144 + s * 64 + q * 16);         \
    float4v acc2[4];                                                          \
    _Pragma("unroll")                                                         \
    for (int t = 0; t < 4; ++t) {                                             \
        acc2[t] = (float4v){0.f, 0.f, 0.f, 0.f};                              \
        _Pragma("unroll")                                                     \
        for (int s = 0; s < 2; ++s) {                                         \
            const short8 w2x = *(const short8*)(wlds + ((s * 4 + t) * 64 + lane) * 16 + idx0); \
            acc2[t] = __builtin_amdgcn_mfma_f32_16x16x32_bf16(a2[s], w2x, acc2[t], 0, 0, 0); \
        }                                                                     \
    }                                                                         \
    _Pragma("unroll")                                                         \
    for (int t = 0; t < 4; ++t)                                               \
        _Pragma("unroll")                                                     \
        for (int r = 0; r < 4; ++r)                                           \
            *(unsigned short*)(hbase + (q * 4 + r) * 144 + (t * 16 + nn) * 2) = \
                f2bf(fmaxf(acc2[t][r], 0.0f));                                \
    short8 a3[2];                                                             \
    _Pragma("unroll")                                                         \
    for (int s = 0; s < 2; ++s)                                               \
        a3[s] = *(const short8*)(hbase + nn * 144 + s * 64 + q * 16);         \
    float4v oc = (float4v){0.f, 0.f, 0.f, 0.f};                               \
    _Pragma("unroll")                                                         \
    for (int s = 0; s < 2; ++s) {                                             \
        const short8 wox = *(const short8*)(wlds + ((8 + s) * 64 + lane) * 16 + idx0); \
        oc = __builtin_amdgcn_mfma_f32_16x16x32_bf16(a3[s], wox, oc, 0, 0, 0); \
    }                                                                         \
    if (nn < 3) {                                                             \
        _Pragma("unroll")                                                     \
        for (int r = 0; r < 4; ++r) {                                         \
            const int pt = (P0) + q * 4 + r;                                  \
            if (pt < N) out[pt * 3 + nn] = oc[r] + bias;                      \
        }                                                                     \
    }                                                                         \
}

__global__ __launch_bounds__(256, 4)
void ingp_mlp_mfma(const unsigned* __restrict__ featbf,  // [NLVL][N]
                   const float*    __restrict__ w0,
                   const float*    __restrict__ w1,
                   const float*    __restrict__ w2,
                   const float*    __restrict__ wout,
                   const float*    __restrict__ bout,
                   float*          __restrict__ out,
                   int N)
{
    __shared__ char lds_raw[4 * 16 * 144];     // per-wave hidden staging
    __shared__ char wlds[(8 + 2) * 64 * 16];   // w2 frags (8KB) + wout frags (2KB)

    const int tid  = (int)threadIdx.x;
    const int wave = tid >> 6;
    const int lane = tid & 63;
    const int q    = lane >> 4;     // quad: K-chunk selector
    const int nn   = lane & 15;     // neuron / point within tile
    char* hbase = lds_raw + wave * (16 * 144);

    // ---- wave 0 stages the (lane-identical-across-waves) w2/wout frags ----
    if (tid < 64) {
        #pragma unroll
        for (int s = 0; s < 2; ++s)
            #pragma unroll
            for (int t = 0; t < 4; ++t) {
                const float* wr2 = w2 + (t * 16 + nn) * 64 + s * 32 + q * 8;
                short8 f;
                #pragma unroll
                for (int e = 0; e < 8; ++e) f[e] = (short)f2bf(wr2[e]);
                *(short8*)(wlds + ((s * 4 + t) * 64 + lane) * 16) = f;
            }
        #pragma unroll
        for (int s = 0; s < 2; ++s) {
            short8 f;
            #pragma unroll
            for (int e = 0; e < 8; ++e)
                f[e] = (nn < 3) ? (short)f2bf(wout[nn * 64 + s * 32 + q * 8 + e])
                                : (short)0;
            *(short8*)(wlds + ((8 + s) * 64 + lane) * 16) = f;
        }
    }
    __syncthreads();

    short8 w0f[4];
    #pragma unroll
    for (int t = 0; t < 4; ++t) {
        const float* wr = w0 + (t * 16 + nn) * 32 + q * 8;
        #pragma unroll
        for (int e = 0; e < 8; ++e) w0f[t][e] = (short)f2bf(wr[e]);
    }
    short8 w1f[2][4];
    #pragma unroll
    for (int s = 0; s < 2; ++s)
        #pragma unroll
        for (int t = 0; t < 4; ++t) {
            const float* wr1 = w1 + (t * 16 + nn) * 64 + s * 32 + q * 8;
            #pragma unroll
            for (int e = 0; e < 8; ++e) w1f[s][t][e] = (short)f2bf(wr1[e]);
        }
    const float bias = (nn < 3) ? bout[nn] : 0.0f;

    int idx0 = 0;   // always 0; laundered per tile (see TILE_BODY)

    const int base = (int)blockIdx.x * 32 + wave * 8;   // tilesPerWave = 8

    // ---- prologue: prefetch tiles 0 and 1 ----
    unsigned ufA[4], ufB[4];
    {
        const int pA = (base * 16 < N) ? (base * 16 + nn) : 0;
        const int pB = ((base + 1) * 16 < N) ? ((base + 1) * 16 + nn) : 0;
        #pragma unroll
        for (int v = 0; v < 4; ++v) {
            ufA[v] = featbf[(size_t)(q * 4 + v) * N + pA];
            ufB[v] = featbf[(size_t)(q * 4 + v) * N + pB];
        }
    }

    for (int it = 0; it < 8; it += 2) {
        const int p0A = (base + it) * 16;
        if (p0A >= N) break;

        // tile it: unpack A-frag, then immediately issue prefetch for it+2
        short8 a0A;
        #pragma unroll
        for (int v = 0; v < 4; ++v) {
            a0A[2 * v]     = (short)(ufA[v] & 0xffffu);
            a0A[2 * v + 1] = (short)(ufA[v] >> 16);
        }
        {
            const int p0n = (base + it + 2) * 16;
            const bool more = (it + 2 < 8) && (p0n < N);
            const int pn = more ? (p0n + nn) : 0;
            #pragma unroll
            for (int v = 0; v < 4; ++v)
                ufA[v] = featbf[(size_t)(q * 4 + v) * N + pn];
        }
        TILE_BODY(p0A, a0A)

        // tile it+1
        const int p0B = (base + it + 1) * 16;
        if (p0B < N) {
            short8 a0B;
            #pragma unroll
            for (int v = 0; v < 4; ++v) {
                a0B[2 * v]     = (short)(ufB[v] & 0xffffu);
                a0B[2 * v + 1] = (short)(ufB[v] >> 16);
            }
            {
                const int p0n = (base + it + 3) * 16;
                const bool more = (it + 3 < 8) && (p0n < N);
                const int pn = more ? (p0n + nn) : 0;
                #pragma unroll
                for (int v = 0; v < 4; ++v)
                    ufB[v] = featbf[(size_t)(q * 4 + v) * N + pn];
            }
            TILE_BODY(p0B, a0B)
        }
    }
}

// ---------------------------------------------------------------------------
// Fallback: round-2 fused kernel (used only if ws is too small for features).
// ---------------------------------------------------------------------------
__global__ __launch_bounds__(256, 2)
void ingp_fused(const float4* __restrict__ x,
                const float2* __restrict__ table,
                const float*  __restrict__ w0,
                const float*  __restrict__ w1,
                const float*  __restrict__ w2,
                const float*  __restrict__ wout,
                const float*  __restrict__ bout,
                float*        __restrict__ out,
                int N, ResArr res)
{
    const int n = blockIdx.x * blockDim.x + threadIdx.x;
    if (n >= N) return;

    const float4 xv = x[n];
    const float px[4] = {xv.x, xv.y, xv.z, xv.w};

    float h1[64];
    #pragma unroll
    for (int j = 0; j < 64; ++j) h1[j] = 0.0f;

    float a0p = 0.0f, a1p = 0.0f;

    #pragma unroll 1
    for (int l = 0; l < NLVL; ++l) {
        int   rm[4], bi[4];
        float fr[4], om[4];
        #pragma unroll
        for (int d = 0; d < 4; ++d) {
            const int r = res.m1[l * 4 + d];
            rm[d] = r;
            const float pos = px[d] * (float)r;
            const float fb  = floorf(pos);
            fr[d] = pos - fb;
            om[d] = 1.0f - fr[d];
            bi[d] = (int)fb;
        }
        const float2* tl = table + (size_t)l * TSZ;

        float2 fv[16];
        float  wt[16];
        #pragma unroll
        for (int c = 0; c < 16; ++c) {
            int c0 = bi[0] + ( c       & 1);
            int c1 = bi[1] + ((c >> 1) & 1);
            int c2 = bi[2] + ((c >> 2) & 1);
            int c3 = bi[3] + ((c >> 3) & 1);
            c0 = min(max(c0, 0), rm[0]);
            c1 = min(max(c1, 0), rm[1]);
            c2 = min(max(c2, 0), rm[2]);
            c3 = min(max(c3, 0), rm[3]);
            const unsigned hh = (unsigned)c0
                              ^ ((unsigned)c1 * 2654435761u)
                              ^ ((unsigned)c2 * 805459861u)
                              ^ ((unsigned)c3 * 3674653429u);
            fv[c] = tl[hh & TMASK];
            float w = ( c       & 1) ? fr[0] : om[0];
            w      *= ((c >> 1) & 1) ? fr[1] : om[1];
            w      *= ((c >> 2) & 1) ? fr[2] : om[2];
            w      *= ((c >> 3) & 1) ? fr[3] : om[3];
            wt[c] = w;
        }
        {
            const int lp = (l == 0) ? 0 : (l - 1);
            const float* w0c = w0 + 2 * lp;
            #pragma unroll
            for (int j = 0; j < 64; ++j)
                h1[j] = fmaf(w0c[j * 32], a0p, fmaf(w0c[j * 32 + 1], a1p, h1[j]));
        }
        float a0 = 0.0f, a1 = 0.0f;
        #pragma unroll
        for (int c = 0; c < 16; ++c) {
            a0 = fmaf(wt[c], fv[c].x, a0);
            a1 = fmaf(wt[c], fv[c].y, a1);
        }
        a0p = a0; a1p = a1;
    }
    {
        const float* w0c = w0 + 2 * (NLVL - 1);
        #pragma unroll
        for (int j = 0; j < 64; ++j)
            h1[j] = fmaf(w0c[j * 32], a0p, fmaf(w0c[j * 32 + 1], a1p, h1[j]));
    }
    #pragma unroll
    for (int j = 0; j < 64; ++j) h1[j] = fmaxf(h1[j], 0.0f);

    float h2[64];
    #pragma unroll
    for (int j = 0; j < 64; ++j) {
        float acc = 0.0f;
        const float* wr = w1 + j * 64;
        #pragma unroll
        for (int i = 0; i < 64; ++i) acc = fmaf(wr[i], h1[i], acc);
        h2[j] = fmaxf(acc, 0.0f);
    }
    float h3[64];
    #pragma unroll
    for (int j = 0; j < 64; ++j) {
        float acc = 0.0f;
        const float* wr = w2 + j * 64;
        #pragma unroll
        for (int i = 0; i < 64; ++i) acc = fmaf(wr[i], h2[i], acc);
        h3[j] = fmaxf(acc, 0.0f);
    }
    float o[3];
    #pragma unroll
    for (int k = 0; k < 3; ++k) {
        float acc = bout[k];
        const float* wr = wout + k * 64;
        #pragma unroll
        for (int i = 0; i < 64; ++i) acc = fmaf(wr[i], h3[i], acc);
        o[k] = acc;
    }
    out[n * 3 + 0] = o[0];
    out[n * 3 + 1] = o[1];
    out[n * 3 + 2] = o[2];
}

extern "C" void kernel_launch(void* const* d_in, const int* in_sizes, int n_in,
                              void* d_out, int out_size, void* d_ws, size_t ws_size,
                              hipStream_t stream) {
    (void)n_in; (void)out_size;

    const float* x     = (const float*)d_in[0];
    const float* table = (const float*)d_in[1];
    const float* w0    = (const float*)d_in[2];
    const float* w1    = (const float*)d_in[3];
    const float* w2    = (const float*)d_in[4];
    const float* wout  = (const float*)d_in[5];
    const float* bout  = (const float*)d_in[6];
    float* out = (float*)d_out;

    const int N = in_sizes[0] / 4;

    // Replicate numpy's float64 resolution computation bit-for-bit (same
    // glibc pow). Levels 5/10/15 of dim 3 sit on exact integer boundaries
    // (8^(5/15)==2), so floor() must see the same double as numpy produced.
    ResArr res;
    for (int d = 0; d < 4; ++d) {
        const double minr = 16.0;
        const double maxr = (d == 3) ? 128.0 : 256.0;
        const double growth = pow(maxr / minr, 1.0 / (double)(NLVL - 1));
        for (int l = 0; l < NLVL; ++l) {
            const int r = (int)floor(minr * pow(growth, (double)l));
            res.m1[l * 4 + d] = r - 1;
        }
    }

    const size_t tblBytes  = (size_t)NLVL * TSZ * sizeof(unsigned);      // 32 MiB
    const size_t featBytes = (size_t)NLVL * (size_t)N * sizeof(unsigned);
    const int chunksPerLevel = (N + 255) / 256;

    if (ws_size >= tblBytes + featBytes) {
        unsigned* tblbf  = (unsigned*)d_ws;
        unsigned* featbf = (unsigned*)((char*)d_ws + tblBytes);

        hipLaunchKernelGGL(cvt_table, dim3(2048), dim3(256), 0, stream,
                           (const float4*)table, (uint2*)tblbf,
                           (int)(NLVL * TSZ / 2));

        hipLaunchKernelGGL(ingp_encode_bf16, dim3(NLVL * chunksPerLevel), dim3(256),
                           0, stream, (const float4*)x, tblbf,
                           featbf, N, chunksPerLevel, res);

        const int tiles  = (N + 15) / 16;
        const int waves  = (tiles + 7) / 8;
        const int blocks = (waves + 3) / 4;
        hipLaunchKernelGGL(ingp_mlp_mfma, dim3(blocks), dim3(256), 0, stream,
                           featbf, w0, w1, w2, wout, bout, out, N);
    } else if (ws_size >= featBytes) {
        unsigned* featbf = (unsigned*)d_ws;
        hipLaunchKernelGGL(ingp_encode_f32, dim3(NLVL * chunksPerLevel), dim3(256),
                           0, stream, (const float4*)x, (const float2*)table,
                           featbf, N, chunksPerLevel, res);

        const int tiles  = (N + 15) / 16;
        const int waves  = (tiles + 7) / 8;
        const int blocks = (waves + 3) / 4;
        hipLaunchKernelGGL(ingp_mlp_mfma, dim3(blocks), dim3(256), 0, stream,
                           featbf, w0, w1, w2, wout, bout, out, N);
    } else {
        hipLaunchKernelGGL(ingp_fused, dim3((N + 255) / 256), dim3(256), 0, stream,
                           (const float4*)x, (const float2*)table,
                           w0, w1, w2, wout, bout, out, N, res);
    }
}

// Round 4
// 728.755 us; speedup vs baseline: 1.2023x; 1.0001x over previous
//
#include <hip/hip_runtime.h>
#include <math.h>

#define NLVL  16
#define TSZ   (1u << 19)
#define TMASK (TSZ - 1u)

struct ResArr { int m1[NLVL * 4]; };  // per level, per dim: res-1

typedef short  short8  __attribute__((ext_vector_type(8)));
typedef float  float4v __attribute__((ext_vector_type(4)));

static __device__ __forceinline__ unsigned short f2bf(float f) {
    unsigned u = __float_as_uint(f);
    return (unsigned short)((u + 0x7fffu + ((u >> 16) & 1u)) >> 16);  // RNE
}

// ---------------------------------------------------------------------------
// Table conversion: f32 pairs (8B/entry) -> packed bf16 pairs (4B/entry).
// Runs once per call (~48 MB of traffic, ~10 us).
// ---------------------------------------------------------------------------
__global__ __launch_bounds__(256)
void cvt_table(const float4* __restrict__ t, uint2* __restrict__ o, int totalPairs)
{
    for (int i = blockIdx.x * 256 + (int)threadIdx.x; i < totalPairs;
         i += gridDim.x * 256) {
        const float4 e = t[i];
        o[i] = make_uint2((unsigned)f2bf(e.x) | ((unsigned)f2bf(e.y) << 16),
                          (unsigned)f2bf(e.z) | ((unsigned)f2bf(e.w) << 16));
    }
}

// ---------------------------------------------------------------------------
// Encode, bf16-table version (verified round-2/3: 577 us, ~96% of the L2
// request-service roofline at ~10 req/point-level).
// ---------------------------------------------------------------------------
static __device__ __forceinline__
void encode_point_bf16(const float4*   __restrict__ x,
                       const unsigned* __restrict__ tbl,     // [NLVL][TSZ] bf16 pairs
                       unsigned*       __restrict__ featbf,  // [NLVL][N] bf16 pairs
                       int N, int l, int n, const ResArr& res)
{
    if (n >= N) return;

    const float4 xv = x[n];
    const float px[4] = {xv.x, xv.y, xv.z, xv.w};

    int   bi[4];
    float fr[4], om[4];
    #pragma unroll
    for (int d = 0; d < 4; ++d) {
        const int r = res.m1[l * 4 + d];       // wave-uniform -> scalar
        const float pos = px[d] * (float)r;
        const float fb  = floorf(pos);
        fr[d] = pos - fb;
        om[d] = 1.0f - fr[d];
        bi[d] = (int)fb;
    }
    const unsigned* tl  = tbl + (size_t)l * TSZ;
    const uint2*    tl2 = (const uint2*)tl;
    const uint4*    tl4 = (const uint4*)tl;

    unsigned hrest[8];
    #pragma unroll
    for (int p = 0; p < 8; ++p) {
        const int c1 = bi[1] + ( p       & 1);
        const int c2 = bi[2] + ((p >> 1) & 1);
        const int c3 = bi[3] + ((p >> 2) & 1);
        hrest[p] = ((unsigned)c1 * 2654435761u)
                 ^ ((unsigned)c2 * 805459861u)
                 ^ ((unsigned)c3 * 3674653429u);
    }

    const int b0 = bi[0];
    unsigned ea[8], eb[8];   // packed bf16 pairs: dim0-offset 0 / offset 1

    if ((b0 & 1) == 0) {
        #pragma unroll
        for (int p = 0; p < 8; ++p) {
            const unsigned h = ((unsigned)b0 ^ hrest[p]) & TMASK;
            const uint2 q = tl2[h >> 1];
            ea[p] = (h & 1u) ? q.y : q.x;
            eb[p] = (h & 1u) ? q.x : q.y;
        }
    } else if ((b0 & 3) == 1) {
        #pragma unroll
        for (int p = 0; p < 8; ++p) {
            const unsigned hA = ((unsigned)b0 ^ hrest[p]) & TMASK;
            const uint4 q = tl4[hA >> 2];
            const unsigned jA  = hA & 3u;
            const unsigned loA = (jA & 2u) ? q.z : q.x;
            const unsigned hiA = (jA & 2u) ? q.w : q.y;
            const unsigned loB = (jA & 2u) ? q.x : q.z;
            const unsigned hiB = (jA & 2u) ? q.y : q.w;
            ea[p] = (jA & 1u) ? hiA : loA;
            eb[p] = (jA & 1u) ? loB : hiB;
        }
    } else {
        #pragma unroll
        for (int p = 0; p < 8; ++p) {
            const unsigned hA = ((unsigned)b0       ^ hrest[p]) & TMASK;
            const unsigned hB = ((unsigned)(b0 + 1) ^ hrest[p]) & TMASK;
            ea[p] = tl[hA];
            eb[p] = tl[hB];
        }
    }

    float2 fv[16];   // fv[2p] = dim0-offset 0, fv[2p+1] = dim0-offset 1
    #pragma unroll
    for (int p = 0; p < 8; ++p) {
        fv[2 * p]     = make_float2(__uint_as_float(ea[p] << 16),
                                    __uint_as_float(ea[p] & 0xffff0000u));
        fv[2 * p + 1] = make_float2(__uint_as_float(eb[p] << 16),
                                    __uint_as_float(eb[p] & 0xffff0000u));
    }

    float wt[16];
    #pragma unroll
    for (int c = 0; c < 16; ++c) {
        float w = ( c       & 1) ? fr[0] : om[0];
        w      *= ((c >> 1) & 1) ? fr[1] : om[1];
        w      *= ((c >> 2) & 1) ? fr[2] : om[2];
        w      *= ((c >> 3) & 1) ? fr[3] : om[3];
        wt[c] = w;
    }

    float a0 = 0.0f, a1 = 0.0f;
    #pragma unroll
    for (int c = 0; c < 16; ++c) {           // same order as reference einsum
        a0 = fmaf(wt[c], fv[c].x, a0);
        a1 = fmaf(wt[c], fv[c].y, a1);
    }
    featbf[(size_t)l * N + n] = (unsigned)f2bf(a0) | ((unsigned)f2bf(a1) << 16);
}

__global__ __launch_bounds__(256, 4)
void ingp_encode_bf16(const float4*   __restrict__ x,
                      const unsigned* __restrict__ tbl,
                      unsigned*       __restrict__ featbf,
                      int N, int chunksPerLevel, ResArr res)
{
    const int l     = blockIdx.x / chunksPerLevel;
    const int chunk = blockIdx.x - l * chunksPerLevel;
    encode_point_bf16(x, tbl, featbf, N, l, chunk * 256 + (int)threadIdx.x, res);
}

// ---------------------------------------------------------------------------
// f32-table encode (fallback when ws can't hold the bf16 table copy).
// ---------------------------------------------------------------------------
static __device__ __forceinline__
void encode_point_f32(const float4* __restrict__ x,
                      const float2* __restrict__ table,
                      unsigned*     __restrict__ featbf,
                      int N, int l, int n, const ResArr& res)
{
    if (n >= N) return;

    const float4 xv = x[n];
    const float px[4] = {xv.x, xv.y, xv.z, xv.w};

    int   bi[4];
    float fr[4], om[4];
    #pragma unroll
    for (int d = 0; d < 4; ++d) {
        const int r = res.m1[l * 4 + d];
        const float pos = px[d] * (float)r;
        const float fb  = floorf(pos);
        fr[d] = pos - fb;
        om[d] = 1.0f - fr[d];
        bi[d] = (int)fb;
    }
    const float2* tl  = table + (size_t)l * TSZ;
    const float4* tl4 = (const float4*)tl;

    unsigned hrest[8];
    #pragma unroll
    for (int p = 0; p < 8; ++p) {
        const int c1 = bi[1] + ( p       & 1);
        const int c2 = bi[2] + ((p >> 1) & 1);
        const int c3 = bi[3] + ((p >> 2) & 1);
        hrest[p] = ((unsigned)c1 * 2654435761u)
                 ^ ((unsigned)c2 * 805459861u)
                 ^ ((unsigned)c3 * 3674653429u);
    }

    float2 fv[16];
    if ((bi[0] & 1) == 0) {
        #pragma unroll
        for (int p = 0; p < 8; ++p) {
            const unsigned h = ((unsigned)bi[0] ^ hrest[p]) & TMASK;
            const float4 q = tl4[h >> 1];
            const bool odd = (h & 1);
            fv[2 * p]     = odd ? make_float2(q.z, q.w) : make_float2(q.x, q.y);
            fv[2 * p + 1] = odd ? make_float2(q.x, q.y) : make_float2(q.z, q.w);
        }
    } else {
        #pragma unroll
        for (int p = 0; p < 8; ++p) {
            const unsigned hA = ((unsigned)bi[0]       ^ hrest[p]) & TMASK;
            const unsigned hB = ((unsigned)(bi[0] + 1) ^ hrest[p]) & TMASK;
            fv[2 * p]     = tl[hA];
            fv[2 * p + 1] = tl[hB];
        }
    }

    float wt[16];
    #pragma unroll
    for (int c = 0; c < 16; ++c) {
        float w = ( c       & 1) ? fr[0] : om[0];
        w      *= ((c >> 1) & 1) ? fr[1] : om[1];
        w      *= ((c >> 2) & 1) ? fr[2] : om[2];
        w      *= ((c >> 3) & 1) ? fr[3] : om[3];
        wt[c] = w;
    }

    float a0 = 0.0f, a1 = 0.0f;
    #pragma unroll
    for (int c = 0; c < 16; ++c) {
        a0 = fmaf(wt[c], fv[c].x, a0);
        a1 = fmaf(wt[c], fv[c].y, a1);
    }
    featbf[(size_t)l * N + n] = (unsigned)f2bf(a0) | ((unsigned)f2bf(a1) << 16);
}

__global__ __launch_bounds__(256, 4)
void ingp_encode_f32(const float4* __restrict__ x,
                     const float2* __restrict__ table,
                     unsigned*     __restrict__ featbf,
                     int N, int chunksPerLevel, ResArr res)
{
    const int l     = blockIdx.x / chunksPerLevel;
    const int chunk = blockIdx.x - l * chunksPerLevel;
    encode_point_f32(x, table, featbf, N, l, chunk * 256 + (int)threadIdx.x, res);
}

// ---------------------------------------------------------------------------
// MFMA MLP — round-4: DUAL-TILE stage interleave. Two tiles (A,B) per wave
// progress through the 4 layer stages together, each with its own LDS
// h-buffer; B's LDS round-trip latency hides under A's MFMA/VALU and vice
// versa (round-3 showed the per-tile serial chain, not occupancy, is the
// limiter). w2/wout frags come from block-shared LDS (wlds), loaded ONCE
// per (s,t) and fed to both tiles' MFMAs. Depth-2 feat prefetch ring kept.
// ---------------------------------------------------------------------------
#define STORE_H(HB, AC)                                                       \
    _Pragma("unroll")                                                         \
    for (int t = 0; t < 4; ++t)                                               \
        _Pragma("unroll")                                                     \
        for (int r = 0; r < 4; ++r)                                           \
            *(unsigned short*)((HB) + (q * 4 + r) * 144 + (t * 16 + nn) * 2) =\
                f2bf(fmaxf((AC)[t][r], 0.0f));

#define READ_A(HB, DST)                                                       \
    _Pragma("unroll")                                                         \
    for (int s = 0; s < 2; ++s)                                               \
        (DST)[s] = *(const short8*)((HB) + nn * 144 + s * 64 + q * 16);

__global__ __launch_bounds__(256, 3)
void ingp_mlp_mfma(const unsigned* __restrict__ featbf,  // [NLVL][N]
                   const float*    __restrict__ w0,
                   const float*    __restrict__ w1,
                   const float*    __restrict__ w2,
                   const float*    __restrict__ wout,
                   const float*    __restrict__ bout,
                   float*          __restrict__ out,
                   int N)
{
    __shared__ char lds_raw[4 * 2 * 16 * 144];   // two h-buffers per wave
    __shared__ char wlds[(8 + 2) * 64 * 16];     // w2 frags (8KB) + wout (2KB)

    const int tid  = (int)threadIdx.x;
    const int wave = tid >> 6;
    const int lane = tid & 63;
    const int q    = lane >> 4;     // quad: K-chunk selector
    const int nn   = lane & 15;     // neuron / point within tile
    char* hbA = lds_raw + wave * (2 * 16 * 144);
    char* hbB = hbA + 16 * 144;

    // ---- wave 0 stages the (lane-identical-across-waves) w2/wout frags ----
    if (tid < 64) {
        #pragma unroll
        for (int s = 0; s < 2; ++s)
            #pragma unroll
            for (int t = 0; t < 4; ++t) {
                const float* wr2 = w2 + (t * 16 + nn) * 64 + s * 32 + q * 8;
                short8 f;
                #pragma unroll
                for (int e = 0; e < 8; ++e) f[e] = (short)f2bf(wr2[e]);
                *(short8*)(wlds + ((s * 4 + t) * 64 + lane) * 16) = f;
            }
        #pragma unroll
        for (int s = 0; s < 2; ++s) {
            short8 f;
            #pragma unroll
            for (int e = 0; e < 8; ++e)
                f[e] = (nn < 3) ? (short)f2bf(wout[nn * 64 + s * 32 + q * 8 + e])
                                : (short)0;
            *(short8*)(wlds + ((8 + s) * 64 + lane) * 16) = f;
        }
    }
    __syncthreads();

    short8 w0f[4];
    #pragma unroll
    for (int t = 0; t < 4; ++t) {
        const float* wr = w0 + (t * 16 + nn) * 32 + q * 8;
        #pragma unroll
        for (int e = 0; e < 8; ++e) w0f[t][e] = (short)f2bf(wr[e]);
    }
    short8 w1f[2][4];
    #pragma unroll
    for (int s = 0; s < 2; ++s)
        #pragma unroll
        for (int t = 0; t < 4; ++t) {
            const float* wr1 = w1 + (t * 16 + nn) * 64 + s * 32 + q * 8;
            #pragma unroll
            for (int e = 0; e < 8; ++e) w1f[s][t][e] = (short)f2bf(wr1[e]);
        }
    const float bias = (nn < 3) ? bout[nn] : 0.0f;

    int idx0 = 0;   // always 0; laundered per pair to block LICM of wlds reads

    const int base = (int)blockIdx.x * 32 + wave * 8;   // tilesPerWave = 8

    // ---- prologue: prefetch tiles 0 and 1 ----
    unsigned ufA[4], ufB[4];
    {
        const int pA = (base * 16 < N) ? (base * 16 + nn) : 0;
        const int pB = ((base + 1) * 16 < N) ? ((base + 1) * 16 + nn) : 0;
        #pragma unroll
        for (int v = 0; v < 4; ++v) {
            ufA[v] = featbf[(size_t)(q * 4 + v) * N + pA];
            ufB[v] = featbf[(size_t)(q * 4 + v) * N + pB];
        }
    }

    for (int it = 0; it < 8; it += 2) {
        const int p0A = (base + it) * 16;
        if (p0A >= N) break;
        const int p0B = (base + it + 1) * 16;
        const bool hasB = (p0B < N);            // wave-uniform

        // unpack both A-frags, then issue both prefetches for it+2 / it+3
        short8 a0A, a0B;
        #pragma unroll
        for (int v = 0; v < 4; ++v) {
            a0A[2 * v]     = (short)(ufA[v] & 0xffffu);
            a0A[2 * v + 1] = (short)(ufA[v] >> 16);
            a0B[2 * v]     = (short)(ufB[v] & 0xffffu);
            a0B[2 * v + 1] = (short)(ufB[v] >> 16);
        }
        {
            const int pA2 = (base + it + 2) * 16;
            const int pB2 = (base + it + 3) * 16;
            const bool mA = (it + 2 < 8) && (pA2 < N);
            const bool mB = (it + 3 < 8) && (pB2 < N);
            const int iA = mA ? (pA2 + nn) : 0;
            const int iB = mB ? (pB2 + nn) : 0;
            #pragma unroll
            for (int v = 0; v < 4; ++v) {
                ufA[v] = featbf[(size_t)(q * 4 + v) * N + iA];
                ufB[v] = featbf[(size_t)(q * 4 + v) * N + iB];
            }
        }

        asm volatile("" : "+v"(idx0));

        // ---- layer 0 ----
        float4v acA[4], acB[4];
        #pragma unroll
        for (int t = 0; t < 4; ++t) {
            acA[t] = (float4v){0.f, 0.f, 0.f, 0.f};
            acA[t] = __builtin_amdgcn_mfma_f32_16x16x32_bf16(a0A, w0f[t], acA[t], 0, 0, 0);
        }
        if (hasB) {
            #pragma unroll
            for (int t = 0; t < 4; ++t) {
                acB[t] = (float4v){0.f, 0.f, 0.f, 0.f};
                acB[t] = __builtin_amdgcn_mfma_f32_16x16x32_bf16(a0B, w0f[t], acB[t], 0, 0, 0);
            }
        }
        STORE_H(hbA, acA)
        if (hasB) { STORE_H(hbB, acB) }
        short8 a1A[2], a1B[2];
        READ_A(hbA, a1A)
        if (hasB) { READ_A(hbB, a1B) }

        // ---- layer 1 ----
        #pragma unroll
        for (int t = 0; t < 4; ++t) {
            acA[t] = (float4v){0.f, 0.f, 0.f, 0.f};
            #pragma unroll
            for (int s = 0; s < 2; ++s)
                acA[t] = __builtin_amdgcn_mfma_f32_16x16x32_bf16(a1A[s], w1f[s][t], acA[t], 0, 0, 0);
        }
        if (hasB) {
            #pragma unroll
            for (int t = 0; t < 4; ++t) {
                acB[t] = (float4v){0.f, 0.f, 0.f, 0.f};
                #pragma unroll
                for (int s = 0; s < 2; ++s)
                    acB[t] = __builtin_amdgcn_mfma_f32_16x16x32_bf16(a1B[s], w1f[s][t], acB[t], 0, 0, 0);
            }
        }
        STORE_H(hbA, acA)
        if (hasB) { STORE_H(hbB, acB) }
        short8 a2A[2], a2B[2];
        READ_A(hbA, a2A)
        if (hasB) { READ_A(hbB, a2B) }

        // ---- layer 2 (weights from wlds, shared across A/B) ----
        #pragma unroll
        for (int t = 0; t < 4; ++t) {
            acA[t] = (float4v){0.f, 0.f, 0.f, 0.f};
            acB[t] = (float4v){0.f, 0.f, 0.f, 0.f};
        }
        #pragma unroll
        for (int s = 0; s < 2; ++s)
            #pragma unroll
            for (int t = 0; t < 4; ++t) {
                const short8 w2x = *(const short8*)(wlds + ((s * 4 + t) * 64 + lane) * 16 + idx0);
                acA[t] = __builtin_amdgcn_mfma_f32_16x16x32_bf16(a2A[s], w2x, acA[t], 0, 0, 0);
                if (hasB)
                    acB[t] = __builtin_amdgcn_mfma_f32_16x16x32_bf16(a2B[s], w2x, acB[t], 0, 0, 0);
            }
        STORE_H(hbA, acA)
        if (hasB) { STORE_H(hbB, acB) }
        short8 a3A[2], a3B[2];
        READ_A(hbA, a3A)
        if (hasB) { READ_A(hbB, a3B) }

        // ---- output layer ----
        float4v ocA = (float4v){0.f, 0.f, 0.f, 0.f};
        float4v ocB = (float4v){0.f, 0.f, 0.f, 0.f};
        #pragma unroll
        for (int s = 0; s < 2; ++s) {
            const short8 wox = *(const short8*)(wlds + ((8 + s) * 64 + lane) * 16 + idx0);
            ocA = __builtin_amdgcn_mfma_f32_16x16x32_bf16(a3A[s], wox, ocA, 0, 0, 0);
            if (hasB)
                ocB = __builtin_amdgcn_mfma_f32_16x16x32_bf16(a3B[s], wox, ocB, 0, 0, 0);
        }
        if (nn < 3) {
            #pragma unroll
            for (int r = 0; r < 4; ++r) {
                const int pt = p0A + q * 4 + r;
                if (pt < N) out[pt * 3 + nn] = ocA[r] + bias;
            }
            if (hasB) {
                #pragma unroll
                for (int r = 0; r < 4; ++r) {
                    const int pt = p0B + q * 4 + r;
                    if (pt < N) out[pt * 3 + nn] = ocB[r] + bias;
                }
            }
        }
    }
}

// ---------------------------------------------------------------------------
// Fallback: round-2 fused kernel (used only if ws is too small for features).
// ---------------------------------------------------------------------------
__global__ __launch_bounds__(256, 2)
void ingp_fused(const float4* __restrict__ x,
                const float2* __restrict__ table,
                const float*  __restrict__ w0,
                const float*  __restrict__ w1,
                const float*  __restrict__ w2,
                const float*  __restrict__ wout,
                const float*  __restrict__ bout,
                float*        __restrict__ out,
                int N, ResArr res)
{
    const int n = blockIdx.x * blockDim.x + threadIdx.x;
    if (n >= N) return;

    const float4 xv = x[n];
    const float px[4] = {xv.x, xv.y, xv.z, xv.w};

    float h1[64];
    #pragma unroll
    for (int j = 0; j < 64; ++j) h1[j] = 0.0f;

    float a0p = 0.0f, a1p = 0.0f;

    #pragma unroll 1
    for (int l = 0; l < NLVL; ++l) {
        int   rm[4], bi[4];
        float fr[4], om[4];
        #pragma unroll
        for (int d = 0; d < 4; ++d) {
            const int r = res.m1[l * 4 + d];
            rm[d] = r;
            const float pos = px[d] * (float)r;
            const float fb  = floorf(pos);
            fr[d] = pos - fb;
            om[d] = 1.0f - fr[d];
            bi[d] = (int)fb;
        }
        const float2* tl = table + (size_t)l * TSZ;

        float2 fv[16];
        float  wt[16];
        #pragma unroll
        for (int c = 0; c < 16; ++c) {
            int c0 = bi[0] + ( c       & 1);
            int c1 = bi[1] + ((c >> 1) & 1);
            int c2 = bi[2] + ((c >> 2) & 1);
            int c3 = bi[3] + ((c >> 3) & 1);
            c0 = min(max(c0, 0), rm[0]);
            c1 = min(max(c1, 0), rm[1]);
            c2 = min(max(c2, 0), rm[2]);
            c3 = min(max(c3, 0), rm[3]);
            const unsigned hh = (unsigned)c0
                              ^ ((unsigned)c1 * 2654435761u)
                              ^ ((unsigned)c2 * 805459861u)
                              ^ ((unsigned)c3 * 3674653429u);
            fv[c] = tl[hh & TMASK];
            float w = ( c       & 1) ? fr[0] : om[0];
            w      *= ((c >> 1) & 1) ? fr[1] : om[1];
            w      *= ((c >> 2) & 1) ? fr[2] : om[2];
            w      *= ((c >> 3) & 1) ? fr[3] : om[3];
            wt[c] = w;
        }
        {
            const int lp = (l == 0) ? 0 : (l - 1);
            const float* w0c = w0 + 2 * lp;
            #pragma unroll
            for (int j = 0; j < 64; ++j)
                h1[j] = fmaf(w0c[j * 32], a0p, fmaf(w0c[j * 32 + 1], a1p, h1[j]));
        }
        float a0 = 0.0f, a1 = 0.0f;
        #pragma unroll
        for (int c = 0; c < 16; ++c) {
            a0 = fmaf(wt[c], fv[c].x, a0);
            a1 = fmaf(wt[c], fv[c].y, a1);
        }
        a0p = a0; a1p = a1;
    }
    {
        const float* w0c = w0 + 2 * (NLVL - 1);
        #pragma unroll
        for (int j = 0; j < 64; ++j)
            h1[j] = fmaf(w0c[j * 32], a0p, fmaf(w0c[j * 32 + 1], a1p, h1[j]));
    }
    #pragma unroll
    for (int j = 0; j < 64; ++j) h1[j] = fmaxf(h1[j], 0.0f);

    float h2[64];
    #pragma unroll
    for (int j = 0; j < 64; ++j) {
        float acc = 0.0f;
        const float* wr = w1 + j * 64;
        #pragma unroll
        for (int i = 0; i < 64; ++i) acc = fmaf(wr[i], h1[i], acc);
        h2[j] = fmaxf(acc, 0.0f);
    }
    float h3[64];
    #pragma unroll
    for (int j = 0; j < 64; ++j) {
        float acc = 0.0f;
        const float* wr = w2 + j * 64;
        #pragma unroll
        for (int i = 0; i < 64; ++i) acc = fmaf(wr[i], h2[i], acc);
        h3[j] = fmaxf(acc, 0.0f);
    }
    float o[3];
    #pragma unroll
    for (int k = 0; k < 3; ++k) {
        float acc = bout[k];
        const float* wr = wout + k * 64;
        #pragma unroll
        for (int i = 0; i < 64; ++i) acc = fmaf(wr[i], h3[i], acc);
        o[k] = acc;
    }
    out[n * 3 + 0] = o[0];
    out[n * 3 + 1] = o[1];
    out[n * 3 + 2] = o[2];
}

extern "C" void kernel_launch(void* const* d_in, const int* in_sizes, int n_in,
                              void* d_out, int out_size, void* d_ws, size_t ws_size,
                              hipStream_t stream) {
    (void)n_in; (void)out_size;

    const float* x     = (const float*)d_in[0];
    const float* table = (const float*)d_in[1];
    const float* w0    = (const float*)d_in[2];
    const float* w1    = (const float*)d_in[3];
    const float* w2    = (const float*)d_in[4];
    const float* wout  = (const float*)d_in[5];
    const float* bout  = (const float*)d_in[6];
    float* out = (float*)d_out;

    const int N = in_sizes[0] / 4;

    // Replicate numpy's float64 resolution computation bit-for-bit (same
    // glibc pow). Levels 5/10/15 of dim 3 sit on exact integer boundaries
    // (8^(5/15)==2), so floor() must see the same double as numpy produced.
    ResArr res;
    for (int d = 0; d < 4; ++d) {
        const double minr = 16.0;
        const double maxr = (d == 3) ? 128.0 : 256.0;
        const double growth = pow(maxr / minr, 1.0 / (double)(NLVL - 1));
        for (int l = 0; l < NLVL; ++l) {
            const int r = (int)floor(minr * pow(growth, (double)l));
            res.m1[l * 4 + d] = r - 1;
        }
    }

    const size_t tblBytes  = (size_t)NLVL * TSZ * sizeof(unsigned);      // 32 MiB
    const size_t featBytes = (size_t)NLVL * (size_t)N * sizeof(unsigned);
    const int chunksPerLevel = (N + 255) / 256;

    if (ws_size >= tblBytes + featBytes) {
        unsigned* tblbf  = (unsigned*)d_ws;
        unsigned* featbf = (unsigned*)((char*)d_ws + tblBytes);

        hipLaunchKernelGGL(cvt_table, dim3(2048), dim3(256), 0, stream,
                           (const float4*)table, (uint2*)tblbf,
                           (int)(NLVL * TSZ / 2));

        hipLaunchKernelGGL(ingp_encode_bf16, dim3(NLVL * chunksPerLevel), dim3(256),
                           0, stream, (const float4*)x, tblbf,
                           featbf, N, chunksPerLevel, res);

        const int tiles  = (N + 15) / 16;
        const int waves  = (tiles + 7) / 8;
        const int blocks = (waves + 3) / 4;
        hipLaunchKernelGGL(ingp_mlp_mfma, dim3(blocks), dim3(256), 0, stream,
                           featbf, w0, w1, w2, wout, bout, out, N);
    } else if (ws_size >= featBytes) {
        unsigned* featbf = (unsigned*)d_ws;
        hipLaunchKernelGGL(ingp_encode_f32, dim3(NLVL * chunksPerLevel), dim3(256),
                           0, stream, (const float4*)x, (const float2*)table,
                           featbf, N, chunksPerLevel, res);

        const int tiles  = (N + 15) / 16;
        const int waves  = (tiles + 7) / 8;
        const int blocks = (waves + 3) / 4;
        hipLaunchKernelGGL(ingp_mlp_mfma, dim3(blocks), dim3(256), 0, stream,
                           featbf, w0, w1, w2, wout, bout, out, N);
    } else {
        hipLaunchKernelGGL(ingp_fused, dim3((N + 255) / 256), dim3(256), 0, stream,
                           (const float4*)x, (const float2*)table,
                           w0, w1, w2, wout, bout, out, N, res);
    }
}